// Round 1
// baseline (990.791 us; speedup 1.0000x reference)
//
#include <hip/hip_runtime.h>
#include <hip/hip_fp16.h>
#include <stdint.h>

#define NNODES 20000
#define EEDGES 320000
#define DD     256
#define NEG_SLOPE 0.2f
#define SCAN_BLOCKS ((NNODES + 255) / 256)

typedef _Float16 half8 __attribute__((ext_vector_type(8)));
typedef _Float16 half4 __attribute__((ext_vector_type(4)));
typedef float f32x4 __attribute__((ext_vector_type(4)));

// ---------------- CSR build ----------------

__global__ void zero_ints_k(int* __restrict__ p, int n) {
    int i = blockIdx.x * 256 + threadIdx.x;
    if (i < n) p[i] = 0;
}

__global__ void hist_k(const int* __restrict__ dst, int* __restrict__ rowptr) {
    int i = blockIdx.x * 256 + threadIdx.x;
    if (i < EEDGES) atomicAdd(&rowptr[dst[i] + 1], 1);
}

__global__ __launch_bounds__(256) void scan1_k(int* __restrict__ rowptr, int* __restrict__ bsums) {
    __shared__ int buf[256];
    int idx = blockIdx.x * 256 + threadIdx.x;
    int v = (idx < NNODES) ? rowptr[idx + 1] : 0;
    buf[threadIdx.x] = v;
    __syncthreads();
#pragma unroll
    for (int off = 1; off < 256; off <<= 1) {
        int t = (threadIdx.x >= (unsigned)off) ? buf[threadIdx.x - off] : 0;
        __syncthreads();
        buf[threadIdx.x] += t;
        __syncthreads();
    }
    if (idx < NNODES) rowptr[idx + 1] = buf[threadIdx.x];
    if (threadIdx.x == 255) bsums[blockIdx.x] = buf[255];
}

__global__ __launch_bounds__(128) void scan2_k(int* __restrict__ bsums) {
    __shared__ int buf[128];
    int v = (threadIdx.x < SCAN_BLOCKS) ? bsums[threadIdx.x] : 0;
    buf[threadIdx.x] = v;
    __syncthreads();
#pragma unroll
    for (int off = 1; off < 128; off <<= 1) {
        int t = (threadIdx.x >= (unsigned)off) ? buf[threadIdx.x - off] : 0;
        __syncthreads();
        buf[threadIdx.x] += t;
        __syncthreads();
    }
    if (threadIdx.x < SCAN_BLOCKS) bsums[threadIdx.x] = buf[threadIdx.x];
}

__global__ void scan3_k(int* __restrict__ rowptr, const int* __restrict__ bsums,
                        int* __restrict__ cursor) {
    int idx = blockIdx.x * 256 + threadIdx.x;
    if (idx < NNODES) {
        int v = rowptr[idx + 1];
        if (blockIdx.x > 0) { v += bsums[blockIdx.x - 1]; rowptr[idx + 1] = v; }
        if (idx + 1 < NNODES) cursor[idx + 1] = v;
        if (idx == 0) cursor[0] = 0;
    }
}

__global__ void scatter_k(const int* __restrict__ src, const int* __restrict__ dst,
                          int* __restrict__ cursor, int* __restrict__ colsrc) {
    int i = blockIdx.x * 256 + threadIdx.x;
    if (i < EEDGES) {
        int d = dst[i];
        int pos = atomicAdd(&cursor[d], 1);
        colsrc[pos] = src[i];
    }
}

// ---------------- fp32 -> fp16 hi/lo split (row-major, for A side) ----------------

__global__ void cvt_split_k(const float* __restrict__ X, _Float16* __restrict__ Xh,
                            _Float16* __restrict__ Xl, int n) {
    int i = blockIdx.x * 256 + threadIdx.x;
    if (i < n) {
        float v = X[i];
        _Float16 hi = (_Float16)v;
        Xh[i] = hi;
        Xl[i] = (_Float16)(v - (float)hi);
    }
}

// ---------------- weight: W[K][N] fp32 -> W^T hi/lo [N][K] fp16 (optional W3 fold) ----

template<bool SUM>
__global__ void cvt_w_k(const float* __restrict__ W, _Float16* __restrict__ Wh,
                        _Float16* __restrict__ Wl) {
    int i = blockIdx.x * 256 + threadIdx.x;   // over 65536
    if (i < DD * DD) {
        int k = i >> 8, n = i & 255;
        float v = W[i];
        if (SUM) v += W[i + DD * DD];
        _Float16 hi = (_Float16)v;
        Wh[n * DD + k] = hi;
        Wl[n * DD + k] = (_Float16)(v - (float)hi);
    }
}

// ---------------- split-fp16 MFMA GEMM, 128x128 tile (m93/m97-class structure) ------
// A: row-major [M][256] fp16 pairs. B: transposed [N=256][K=256] fp16 pairs.
// Block: 256 threads = 4 waves, 2x2 wave grid, each wave 64x64 output (4x4 of
// mfma_f32_16x16x32_f16 tiles, 4 split products each -> full (hi+lo)x(hi+lo)).
// LDS: 4 linear [128][64]-half tiles (16 KB each, 64 KB total -> 2 blocks/CU),
// XOR-swizzled (slot ^= row&7, G4 fix) identically on write and read:
//   stage:  thread t, round i: row = i*32+(t>>3), src slot ss=t&7,
//           dst halves = row*64 + ((ss^(row&7))<<3)       (conflict-free b128 writes)
//   read:   frag (row r, colseg c): halves = r*64 + ((c^(r&7))<<3)  (2-way = free)
// Staging = register prefetch (proven pattern from the 64x64 version): load stage
// s+1 into int4 regs while MFMAing stage s; 2 barriers per 64-K stage (vs per 32).
// A rows >= M read garbage (in-workspace: P*h overruns into the adjacent P*l
// buffer) and are masked only at the C-write -> no guards on the hot path.

template<bool OUT_SPLIT>
__global__ __launch_bounds__(256, 2) void gemm128_k(
    const _Float16* __restrict__ Ah, const _Float16* __restrict__ Al,
    const _Float16* __restrict__ Bh, const _Float16* __restrict__ Bl,
    float* __restrict__ C, _Float16* __restrict__ Ch, _Float16* __restrict__ Cl, int M)
{
    __shared__ _Float16 sAh[128 * 64], sAl[128 * 64], sBh[128 * 64], sBl[128 * 64];
    const int t = threadIdx.x;
    const int lane = t & 63;
    const int w = t >> 6;
    const int rowBase = blockIdx.y * 128;
    const int colBase = blockIdx.x * 128;
    const int mo = (w & 1) * 64;
    const int no = (w >> 1) * 64;

    const int srow0 = t >> 3;                       // 0..31 (row within 32-row round)
    const int ss8   = (t & 7) * 8;                  // source slot, halves
    const int ds8   = ((t & 7) ^ (srow0 & 7)) * 8;  // swizzled dest slot, halves

    f32x4 acc[4][4];
#pragma unroll
    for (int m = 0; m < 4; ++m)
#pragma unroll
        for (int n = 0; n < 4; ++n) acc[m][n] = (f32x4){0.f, 0.f, 0.f, 0.f};

    int4 pa_h[4], pa_l[4], pb_h[4], pb_l[4];

#define LOADSTAGE(S) \
    _Pragma("unroll") \
    for (int i = 0; i < 4; ++i) { \
        int row = i * 32 + srow0; \
        size_t aoff = (size_t)(rowBase + row) * DD + (S) * 64 + ss8; \
        size_t boff = (size_t)(colBase + row) * DD + (S) * 64 + ss8; \
        pa_h[i] = *(const int4*)(Ah + aoff); \
        pa_l[i] = *(const int4*)(Al + aoff); \
        pb_h[i] = *(const int4*)(Bh + boff); \
        pb_l[i] = *(const int4*)(Bl + boff); \
    }

#define WRITESTAGE() \
    _Pragma("unroll") \
    for (int i = 0; i < 4; ++i) { \
        int lo = (i * 32 + srow0) * 64 + ds8; \
        *(int4*)(sAh + lo) = pa_h[i]; \
        *(int4*)(sAl + lo) = pa_l[i]; \
        *(int4*)(sBh + lo) = pb_h[i]; \
        *(int4*)(sBl + lo) = pb_l[i]; \
    }

    LOADSTAGE(0);
    const int fr = lane & 15;
    const int fq = lane >> 4;

    for (int s = 0; s < 4; ++s) {
        __syncthreads();
        WRITESTAGE();
        __syncthreads();
        if (s < 3) { LOADSTAGE(s + 1); }

#pragma unroll
        for (int kk = 0; kk < 2; ++kk) {
            half8 ah[4], al[4], bh[4], bl[4];
#pragma unroll
            for (int m = 0; m < 4; ++m) {
                int ra = mo + m * 16 + fr;
                int oa = ra * 64 + (((kk * 4 + fq) ^ (ra & 7)) << 3);
                ah[m] = *(const half8*)(sAh + oa);
                al[m] = *(const half8*)(sAl + oa);
                int rb = no + m * 16 + fr;
                int ob = rb * 64 + (((kk * 4 + fq) ^ (rb & 7)) << 3);
                bh[m] = *(const half8*)(sBh + ob);
                bl[m] = *(const half8*)(sBl + ob);
            }
#pragma unroll
            for (int m = 0; m < 4; ++m)
#pragma unroll
                for (int n = 0; n < 4; ++n) {
                    acc[m][n] = __builtin_amdgcn_mfma_f32_16x16x32_f16(ah[m], bh[n], acc[m][n], 0, 0, 0);
                    acc[m][n] = __builtin_amdgcn_mfma_f32_16x16x32_f16(ah[m], bl[n], acc[m][n], 0, 0, 0);
                    acc[m][n] = __builtin_amdgcn_mfma_f32_16x16x32_f16(al[m], bh[n], acc[m][n], 0, 0, 0);
                    acc[m][n] = __builtin_amdgcn_mfma_f32_16x16x32_f16(al[m], bl[n], acc[m][n], 0, 0, 0);
                }
        }
    }
#undef LOADSTAGE
#undef WRITESTAGE

    // C/D layout (verified): col = lane&15, row = (lane>>4)*4 + reg
    const int ccol = lane & 15;
    const int crq = (lane >> 4) * 4;
#pragma unroll
    for (int m = 0; m < 4; ++m) {
        int growb = rowBase + mo + m * 16 + crq;
#pragma unroll
        for (int n = 0; n < 4; ++n) {
            int gcol = colBase + no + n * 16 + ccol;
#pragma unroll
            for (int r = 0; r < 4; ++r) {
                int grow = growb + r;
                if (grow < M) {
                    float v = acc[m][n][r];
                    if (OUT_SPLIT) {
                        _Float16 hi = (_Float16)v;
                        Ch[(size_t)grow * DD + gcol] = hi;
                        Cl[(size_t)grow * DD + gcol] = (_Float16)(v - (float)hi);
                    } else {
                        C[(size_t)grow * DD + gcol] = v;
                    }
                }
            }
        }
    }
}

// ---------------- per-node attention dots (reads fp32 hw) ----------------

__global__ __launch_bounds__(256) void dots_k(const float* __restrict__ hw,
                                              const float* __restrict__ asrc,
                                              const float* __restrict__ adst,
                                              float* __restrict__ es, float* __restrict__ ed) {
    int wave = threadIdx.x >> 6;
    int lane = threadIdx.x & 63;
    int node = blockIdx.x * 4 + wave;
    if (node >= NNODES) return;
    float4 v = *(const float4*)(hw + (size_t)node * DD + lane * 4);
    float4 a = *(const float4*)(asrc + lane * 4);
    float4 b = *(const float4*)(adst + lane * 4);
    float s = v.x * a.x + v.y * a.y + v.z * a.z + v.w * a.w;
    float d = v.x * b.x + v.y * b.y + v.z * b.z + v.w * b.w;
#pragma unroll
    for (int off = 32; off; off >>= 1) {
        s += __shfl_xor(s, off);
        d += __shfl_xor(d, off);
    }
    if (lane == 0) { es[node] = s; ed[node] = d; }
}

// ---------------- fused segment softmax + aggregation; writes fp16 hi/lo split ----
// Pipeline rationale (this round): baseline VGPR_Count=36 proved the compiler had
// register-minimized the gather to ~1-2 outstanding loads/wave (latency-bound:
// MfmaUtil 0, VALU 23%, HBM 43%). Now: explicit 2-deep 8-row double buffer
// (va/vb register sets, no copies) + sched_barrier(0) pinning all 8 next-batch
// load issues before the current batch's FMAs. Batches padded to 8 with w==0
// lanes gathering row 0 (L1-hot, exact-zero contribution) -> no tail code.
// __launch_bounds__(256,4) keeps VGPR <= 128 (16 waves/CU band).

template<bool RELU>
__global__ __launch_bounds__(256, 4) void gat_agg_k(const float* __restrict__ hw,
                                                    const float* __restrict__ es,
                                                    const float* __restrict__ ed,
                                                    const int* __restrict__ rowptr,
                                                    const int* __restrict__ colsrc,
                                                    float* __restrict__ ealpha,
                                                    const float* __restrict__ bias,
                                                    _Float16* __restrict__ hh,
                                                    _Float16* __restrict__ hl) {
    int wave = threadIdx.x >> 6;
    int lane = threadIdx.x & 63;
    int node = blockIdx.x * 4 + wave;
    if (node >= NNODES) return;
    int start = rowptr[node], end = rowptr[node + 1];
    int deg = end - start;
    float edd = ed[node];

    float4 acc0 = make_float4(0.f, 0.f, 0.f, 0.f);
    float4 acc1 = acc0, acc2 = acc0, acc3 = acc0;

#define FMA4(ACC, W_, V) \
    ACC.x = fmaf(W_, V.x, ACC.x); ACC.y = fmaf(W_, V.y, ACC.y); \
    ACC.z = fmaf(W_, V.z, ACC.z); ACC.w = fmaf(W_, V.w, ACC.w);

    if (deg > 0 && deg <= 64) {
        bool valid = lane < deg;
        int msrc = valid ? colsrc[start + lane] : 0;
        float e = valid ? es[msrc] + edd : -INFINITY;
        e = fmaxf(e, NEG_SLOPE * e);
        float mx = e;
#pragma unroll
        for (int off = 32; off; off >>= 1) mx = fmaxf(mx, __shfl_xor(mx, off));
        float ee = valid ? expf(e - mx) : 0.f;
        float sum = ee;
#pragma unroll
        for (int off = 32; off; off >>= 1) sum += __shfl_xor(sum, off);
        float w = ee / sum;   // exactly 0 for pad lanes

#define FETCH8(V, W_, JB) \
        _Pragma("unroll") \
        for (int q = 0; q < 8; ++q) { \
            int sq = __shfl(msrc, (JB) + q); \
            W_[q] = __shfl(w, (JB) + q); \
            V[q] = *(const float4*)(hw + (size_t)sq * DD + lane * 4); \
        }

#define FMA8(V, W_) \
        FMA4(acc0, W_[0], V[0]); FMA4(acc1, W_[1], V[1]); \
        FMA4(acc2, W_[2], V[2]); FMA4(acc3, W_[3], V[3]); \
        FMA4(acc0, W_[4], V[4]); FMA4(acc1, W_[5], V[5]); \
        FMA4(acc2, W_[6], V[6]); FMA4(acc3, W_[7], V[7]);

        float4 va[8], vb[8];
        float wa[8], wb[8];
        FETCH8(va, wa, 0);
        int jb = 8;
        for (;;) {
            if (jb >= deg) { FMA8(va, wa); break; }
            FETCH8(vb, wb, jb); jb += 8;
            __builtin_amdgcn_sched_barrier(0);   // pin: vb loads issued before va FMAs
            FMA8(va, wa);
            if (jb >= deg) { FMA8(vb, wb); break; }
            FETCH8(va, wa, jb); jb += 8;
            __builtin_amdgcn_sched_barrier(0);
            FMA8(vb, wb);
        }
#undef FETCH8
#undef FMA8
    } else if (deg > 64) {
        float mx = -INFINITY;
        for (int j = start + lane; j < end; j += 64) {
            float e = es[colsrc[j]] + edd;
            e = fmaxf(e, NEG_SLOPE * e);
            mx = fmaxf(mx, e);
        }
#pragma unroll
        for (int off = 32; off; off >>= 1) mx = fmaxf(mx, __shfl_xor(mx, off));
        float sum = 0.f;
        for (int j = start + lane; j < end; j += 64) {
            float e = es[colsrc[j]] + edd;
            e = fmaxf(e, NEG_SLOPE * e);
            float ee = expf(e - mx);
            ealpha[j] = ee;
            sum += ee;
        }
#pragma unroll
        for (int off = 32; off; off >>= 1) sum += __shfl_xor(sum, off);
        float inv = 1.f / sum;
        int j = start;
        for (; j + 4 <= end; j += 4) {
            int s0 = colsrc[j], s1 = colsrc[j + 1], s2 = colsrc[j + 2], s3 = colsrc[j + 3];
            float w0 = ealpha[j] * inv, w1 = ealpha[j + 1] * inv;
            float w2 = ealpha[j + 2] * inv, w3 = ealpha[j + 3] * inv;
            float4 v0 = *(const float4*)(hw + (size_t)s0 * DD + lane * 4);
            float4 v1 = *(const float4*)(hw + (size_t)s1 * DD + lane * 4);
            float4 v2 = *(const float4*)(hw + (size_t)s2 * DD + lane * 4);
            float4 v3 = *(const float4*)(hw + (size_t)s3 * DD + lane * 4);
            FMA4(acc0, w0, v0); FMA4(acc1, w1, v1);
            FMA4(acc2, w2, v2); FMA4(acc3, w3, v3);
        }
        for (; j < end; ++j) {
            int s0 = colsrc[j];
            float w0 = ealpha[j] * inv;
            float4 v0 = *(const float4*)(hw + (size_t)s0 * DD + lane * 4);
            FMA4(acc0, w0, v0);
        }
    }
#undef FMA4

    acc0.x += acc1.x; acc0.y += acc1.y; acc0.z += acc1.z; acc0.w += acc1.w;
    acc2.x += acc3.x; acc2.y += acc3.y; acc2.z += acc3.z; acc2.w += acc3.w;
    acc0.x += acc2.x; acc0.y += acc2.y; acc0.z += acc2.z; acc0.w += acc2.w;
    float4 b4 = *(const float4*)(bias + lane * 4);
    acc0.x += b4.x; acc0.y += b4.y; acc0.z += b4.z; acc0.w += b4.w;
    if (RELU) {
        acc0.x = fmaxf(acc0.x, 0.f); acc0.y = fmaxf(acc0.y, 0.f);
        acc0.z = fmaxf(acc0.z, 0.f); acc0.w = fmaxf(acc0.w, 0.f);
    }
    size_t base = (size_t)node * DD + lane * 4;
    _Float16 h0 = (_Float16)acc0.x, h1 = (_Float16)acc0.y;
    _Float16 h2 = (_Float16)acc0.z, h3 = (_Float16)acc0.w;
    half4 hv; hv[0] = h0; hv[1] = h1; hv[2] = h2; hv[3] = h3;
    half4 lv;
    lv[0] = (_Float16)(acc0.x - (float)h0); lv[1] = (_Float16)(acc0.y - (float)h1);
    lv[2] = (_Float16)(acc0.z - (float)h2); lv[3] = (_Float16)(acc0.w - (float)h3);
    *(half4*)(hh + base) = hv;
    *(half4*)(hl + base) = lv;
}

// ---------------- driver ----------------

extern "C" void kernel_launch(void* const* d_in, const int* in_sizes, int n_in,
                              void* d_out, int out_size, void* d_ws, size_t ws_size,
                              hipStream_t stream) {
    const float* x     = (const float*)d_in[0];
    const int*   ei    = (const int*)d_in[1];     // [2,E]: src then dst
    const float* W1    = (const float*)d_in[2];
    const float* W2    = (const float*)d_in[3];
    const float* Ws    = (const float*)d_in[4];   // [6,256,256]
    const float* a_src = (const float*)d_in[5];
    const float* a_dst = (const float*)d_in[6];
    const float* bias  = (const float*)d_in[7];
    const float* W3    = (const float*)d_in[8];   // [512,256]
    float* out = (float*)d_out;

    const int* src = ei;
    const int* dst = ei + EEDGES;

    const size_t ND = (size_t)NNODES * DD;

    // workspace carve-up
    float* bufA   = (float*)d_ws;            // ND fp32 (hw)
    float* es     = bufA + ND;               // N
    float* edv    = es + NNODES;             // N
    float* ealpha = edv + NNODES;            // E
    int*   rowptr = (int*)(ealpha + EEDGES); // N+1
    int*   cursor = rowptr + (NNODES + 1);   // N
    int*   colsrc = cursor + NNODES;         // E
    int*   bsums  = colsrc + EEDGES;         // SCAN_BLOCKS
    _Float16* P0h = (_Float16*)(((uintptr_t)(bsums + SCAN_BLOCKS) + 15) & ~(uintptr_t)15);
    _Float16* P0l = P0h + ND;
    _Float16* P1h = P0l + ND;
    _Float16* P1l = P1h + ND;
    _Float16* WT  = P1l + ND;                // 9 weight pairs (transposed split)
    const size_t WSZ = (size_t)DD * DD;      // 65536

    // --- CSR build ---
    zero_ints_k<<<(NNODES + 1 + 255) / 256, 256, 0, stream>>>(rowptr, NNODES + 1);
    hist_k<<<(EEDGES + 255) / 256, 256, 0, stream>>>(dst, rowptr);
    scan1_k<<<SCAN_BLOCKS, 256, 0, stream>>>(rowptr, bsums);
    scan2_k<<<1, 128, 0, stream>>>(bsums);
    scan3_k<<<SCAN_BLOCKS, 256, 0, stream>>>(rowptr, bsums, cursor);
    scatter_k<<<(EEDGES + 255) / 256, 256, 0, stream>>>(src, dst, cursor, colsrc);

    // --- weight conversion (transpose + fp16 split) ---
    const int WBLK = (DD * DD + 255) / 256;
    cvt_w_k<false><<<WBLK, 256, 0, stream>>>(W1, WT + 0 * 2 * WSZ, WT + 0 * 2 * WSZ + WSZ);
    cvt_w_k<false><<<WBLK, 256, 0, stream>>>(W2, WT + 1 * 2 * WSZ, WT + 1 * 2 * WSZ + WSZ);
    for (int l = 0; l < 6; ++l)
        cvt_w_k<false><<<WBLK, 256, 0, stream>>>(Ws + (size_t)l * WSZ,
                                                 WT + (2 + l) * 2 * WSZ,
                                                 WT + (2 + l) * 2 * WSZ + WSZ);
    cvt_w_k<true><<<WBLK, 256, 0, stream>>>(W3, WT + 8 * 2 * WSZ, WT + 8 * 2 * WSZ + WSZ);

    // --- x split ---
    cvt_split_k<<<(int)((ND + 255) / 256), 256, 0, stream>>>(x, P0h, P0l, (int)ND);

    dim3 g128(DD / 128, (NNODES + 127) / 128);   // (2, 157)
    const int nodeBlocks = (NNODES + 3) / 4;

#define WTH(i) (WT + (i) * 2 * WSZ)
#define WTL(i) (WT + (i) * 2 * WSZ + WSZ)

    // t = x@W1 (split out), h0 = t@W2 (split out)
    gemm128_k<true><<<g128, 256, 0, stream>>>(P0h, P0l, WTH(0), WTL(0), nullptr, P1h, P1l, NNODES);
    gemm128_k<true><<<g128, 256, 0, stream>>>(P1h, P1l, WTH(1), WTL(1), nullptr, P0h, P0l, NNODES);

    // 6 GAT layers: h (P0 split) -> hw (bufA fp32) -> agg -> h (P0 split)
    for (int l = 0; l < 6; ++l) {
        gemm128_k<false><<<g128, 256, 0, stream>>>(P0h, P0l, WTH(2 + l), WTL(2 + l),
                                                   bufA, nullptr, nullptr, NNODES);
        dots_k<<<nodeBlocks, 256, 0, stream>>>(bufA, a_src + (size_t)l * DD,
                                               a_dst + (size_t)l * DD, es, edv);
        if (l < 5)
            gat_agg_k<false><<<nodeBlocks, 256, 0, stream>>>(bufA, es, edv, rowptr, colsrc,
                                                             ealpha, bias + (size_t)l * DD,
                                                             P0h, P0l);
        else
            gat_agg_k<true><<<nodeBlocks, 256, 0, stream>>>(bufA, es, edv, rowptr, colsrc,
                                                            ealpha, bias + (size_t)l * DD,
                                                            P0h, P0l);
    }

    // out = relu(h) @ (W3_top + W3_bot)  (relu already applied in layer-5 agg)
    gemm128_k<false><<<g128, 256, 0, stream>>>(P0h, P0l, WTH(8), WTL(8), out,
                                               nullptr, nullptr, NNODES);
#undef WTH
#undef WTL
}

// Round 2
// 678.680 us; speedup vs baseline: 1.4599x; 1.4599x over previous
//
#include <hip/hip_runtime.h>
#include <hip/hip_fp16.h>
#include <stdint.h>

#define NNODES 20000
#define EEDGES 320000
#define DD     256
#define NEG_SLOPE 0.2f
#define SCAN_BLOCKS ((NNODES + 255) / 256)

typedef _Float16 half8 __attribute__((ext_vector_type(8)));
typedef _Float16 half4 __attribute__((ext_vector_type(4)));
typedef float f32x4 __attribute__((ext_vector_type(4)));

// ---------------- CSR build ----------------

__global__ void zero_ints_k(int* __restrict__ p, int n) {
    int i = blockIdx.x * 256 + threadIdx.x;
    if (i < n) p[i] = 0;
}

__global__ void hist_k(const int* __restrict__ dst, int* __restrict__ rowptr) {
    int i = blockIdx.x * 256 + threadIdx.x;
    if (i < EEDGES) atomicAdd(&rowptr[dst[i] + 1], 1);
}

__global__ __launch_bounds__(256) void scan1_k(int* __restrict__ rowptr, int* __restrict__ bsums) {
    __shared__ int buf[256];
    int idx = blockIdx.x * 256 + threadIdx.x;
    int v = (idx < NNODES) ? rowptr[idx + 1] : 0;
    buf[threadIdx.x] = v;
    __syncthreads();
#pragma unroll
    for (int off = 1; off < 256; off <<= 1) {
        int t = (threadIdx.x >= (unsigned)off) ? buf[threadIdx.x - off] : 0;
        __syncthreads();
        buf[threadIdx.x] += t;
        __syncthreads();
    }
    if (idx < NNODES) rowptr[idx + 1] = buf[threadIdx.x];
    if (threadIdx.x == 255) bsums[blockIdx.x] = buf[255];
}

__global__ __launch_bounds__(128) void scan2_k(int* __restrict__ bsums) {
    __shared__ int buf[128];
    int v = (threadIdx.x < SCAN_BLOCKS) ? bsums[threadIdx.x] : 0;
    buf[threadIdx.x] = v;
    __syncthreads();
#pragma unroll
    for (int off = 1; off < 128; off <<= 1) {
        int t = (threadIdx.x >= (unsigned)off) ? buf[threadIdx.x - off] : 0;
        __syncthreads();
        buf[threadIdx.x] += t;
        __syncthreads();
    }
    if (threadIdx.x < SCAN_BLOCKS) bsums[threadIdx.x] = buf[threadIdx.x];
}

__global__ void scan3_k(int* __restrict__ rowptr, const int* __restrict__ bsums,
                        int* __restrict__ cursor) {
    int idx = blockIdx.x * 256 + threadIdx.x;
    if (idx < NNODES) {
        int v = rowptr[idx + 1];
        if (blockIdx.x > 0) { v += bsums[blockIdx.x - 1]; rowptr[idx + 1] = v; }
        if (idx + 1 < NNODES) cursor[idx + 1] = v;
        if (idx == 0) cursor[0] = 0;
    }
}

__global__ void scatter_k(const int* __restrict__ src, const int* __restrict__ dst,
                          int* __restrict__ cursor, int* __restrict__ colsrc) {
    int i = blockIdx.x * 256 + threadIdx.x;
    if (i < EEDGES) {
        int d = dst[i];
        int pos = atomicAdd(&cursor[d], 1);
        colsrc[pos] = src[i];
    }
}

// ---------------- fp32 -> fp16 hi/lo split (row-major, for A side) ----------------

__global__ void cvt_split_k(const float* __restrict__ X, _Float16* __restrict__ Xh,
                            _Float16* __restrict__ Xl, int n) {
    int i = blockIdx.x * 256 + threadIdx.x;
    if (i < n) {
        float v = X[i];
        _Float16 hi = (_Float16)v;
        Xh[i] = hi;
        Xl[i] = (_Float16)(v - (float)hi);
    }
}

// ---------------- weight: W[K][N] fp32 -> W^T hi/lo [N][K] fp16 (optional W3 fold) ----

template<bool SUM>
__global__ void cvt_w_k(const float* __restrict__ W, _Float16* __restrict__ Wh,
                        _Float16* __restrict__ Wl) {
    int i = blockIdx.x * 256 + threadIdx.x;   // over 65536
    if (i < DD * DD) {
        int k = i >> 8, n = i & 255;
        float v = W[i];
        if (SUM) v += W[i + DD * DD];
        _Float16 hi = (_Float16)v;
        Wh[n * DD + k] = hi;
        Wl[n * DD + k] = (_Float16)(v - (float)hi);
    }
}

// ---------------- split-fp16 MFMA GEMM, 64x128 tile, 512 threads ----------------
// R1 post-mortem: 128x128 tile -> 314 blocks x 4 waves = occupancy starvation
// (Occupancy 8%, MfmaUtil 6%). This shape: grid = 2 x 313 = 626 blocks x 8 waves
// = ~19 waves/CU, LDS 48KB (3 blocks/CU capacity). A re-fetched only 2x.
// Wave grid 2x4, wave tile 32x32 (2x2 frags x 4 split products = 16 MFMA/kk).
// XOR swizzle (slot ^ row&7) on LDS write+read: 2-way banks = free (G4).
// OUT_SPLIT epilogue bounces through LDS (pitch 136 halves) -> coalesced half8
// stores; R1 measured the direct 2B-scatter path at 76MB WRITE vs 20.5 logical.

template<bool OUT_SPLIT>
__global__ __launch_bounds__(512, 4) void gemm_k(
    const _Float16* __restrict__ Ah, const _Float16* __restrict__ Al,
    const _Float16* __restrict__ Bh, const _Float16* __restrict__ Bl,
    float* __restrict__ C, _Float16* __restrict__ Ch, _Float16* __restrict__ Cl, int M)
{
    // carve-up (halves): A_h 0..4096, A_l 4096..8192, B_h 8192..16384, B_l 16384..24576
    __shared__ _Float16 smem[24576];
    _Float16* sAh = smem;
    _Float16* sAl = smem + 4096;
    _Float16* sBh = smem + 8192;
    _Float16* sBl = smem + 16384;

    const int t = threadIdx.x;          // 0..511
    const int lane = t & 63;
    const int w = t >> 6;               // 0..7
    const int rowBase = blockIdx.y * 64;
    const int colBase = blockIdx.x * 128;
    const int mo = (w & 1) * 32;        // wave row offset (2 row-waves)
    const int no = (w >> 1) * 32;       // wave col offset (4 col-waves)

    const int arow = t >> 3;            // 0..63
    const int slot = t & 7;             // 0..7 (16B slots per 64-half row)
    const int swz = (slot ^ (arow & 7)) << 3;   // swizzled half-offset within row

    f32x4 acc[2][2];
#pragma unroll
    for (int m = 0; m < 2; ++m)
#pragma unroll
        for (int n = 0; n < 2; ++n) acc[m][n] = (f32x4){0.f, 0.f, 0.f, 0.f};

    int4 pa_h, pa_l, pb_h0, pb_h1, pb_l0, pb_l1;

#define LOADSTAGE(S) { \
        size_t aoff  = (size_t)(rowBase + arow) * DD + (S) * 64 + slot * 8; \
        size_t boff0 = (size_t)(colBase + arow) * DD + (S) * 64 + slot * 8; \
        size_t boff1 = boff0 + (size_t)64 * DD; \
        pa_h  = *(const int4*)(Ah + aoff); \
        pa_l  = *(const int4*)(Al + aoff); \
        pb_h0 = *(const int4*)(Bh + boff0); \
        pb_h1 = *(const int4*)(Bh + boff1); \
        pb_l0 = *(const int4*)(Bl + boff0); \
        pb_l1 = *(const int4*)(Bl + boff1); \
    }

#define WRITESTAGE() { \
        int da  = arow * 64 + swz; \
        *(int4*)(sAh + da) = pa_h; \
        *(int4*)(sAl + da) = pa_l; \
        *(int4*)(sBh + da) = pb_h0; \
        *(int4*)(sBh + da + 4096) = pb_h1; \
        *(int4*)(sBl + da) = pb_l0; \
        *(int4*)(sBl + da + 4096) = pb_l1; \
    }

    LOADSTAGE(0);
    const int fr = lane & 15;
    const int fq = lane >> 4;

    for (int s = 0; s < 4; ++s) {
        __syncthreads();
        WRITESTAGE();
        __syncthreads();
        if (s < 3) { LOADSTAGE(s + 1); }

#pragma unroll
        for (int kk = 0; kk < 2; ++kk) {
            const int c = kk * 4 + fq;
            half8 ah[2], al[2], bh[2], bl[2];
#pragma unroll
            for (int m = 0; m < 2; ++m) {
                int ra = mo + m * 16 + fr;
                int oa = ra * 64 + ((c ^ (ra & 7)) << 3);
                ah[m] = *(const half8*)(sAh + oa);
                al[m] = *(const half8*)(sAl + oa);
            }
#pragma unroll
            for (int n = 0; n < 2; ++n) {
                int rb = no + n * 16 + fr;
                int ob = rb * 64 + ((c ^ (rb & 7)) << 3);
                bh[n] = *(const half8*)(sBh + ob);
                bl[n] = *(const half8*)(sBl + ob);
            }
#pragma unroll
            for (int m = 0; m < 2; ++m)
#pragma unroll
                for (int n = 0; n < 2; ++n) {
                    acc[m][n] = __builtin_amdgcn_mfma_f32_16x16x32_f16(ah[m], bh[n], acc[m][n], 0, 0, 0);
                    acc[m][n] = __builtin_amdgcn_mfma_f32_16x16x32_f16(ah[m], bl[n], acc[m][n], 0, 0, 0);
                    acc[m][n] = __builtin_amdgcn_mfma_f32_16x16x32_f16(al[m], bh[n], acc[m][n], 0, 0, 0);
                    acc[m][n] = __builtin_amdgcn_mfma_f32_16x16x32_f16(al[m], bl[n], acc[m][n], 0, 0, 0);
                }
        }
    }
#undef LOADSTAGE
#undef WRITESTAGE

    // C/D layout (verified): col = lane&15, row = (lane>>4)*4 + reg
    const int ccol = lane & 15;
    const int crq = (lane >> 4) * 4;

    if (OUT_SPLIT) {
        // bounce via LDS: pitch 136 halves (272B, 16B-aligned rows, bank-spread)
        __syncthreads();   // all staged-LDS reads done before overwrite
#pragma unroll
        for (int m = 0; m < 2; ++m)
#pragma unroll
            for (int n = 0; n < 2; ++n)
#pragma unroll
                for (int r = 0; r < 4; ++r) {
                    int row = mo + m * 16 + crq + r;        // 0..63
                    int col = no + n * 16 + ccol;           // 0..127
                    float v = acc[m][n][r];
                    _Float16 hi = (_Float16)v;
                    smem[row * 136 + col] = hi;
                    smem[8704 + row * 136 + col] = (_Float16)(v - (float)hi);
                }
        __syncthreads();
#pragma unroll
        for (int i = 0; i < 2; ++i) {
            int slotId = i * 512 + t;         // 0..1023
            int srow = slotId >> 4;           // 0..63
            int sc = slotId & 15;             // 16B chunk within 128-half row
            int grow = rowBase + srow;
            if (grow < M) {
                half8 hv = *(const half8*)(smem + srow * 136 + sc * 8);
                half8 lv = *(const half8*)(smem + 8704 + srow * 136 + sc * 8);
                *(half8*)(Ch + (size_t)grow * DD + colBase + sc * 8) = hv;
                *(half8*)(Cl + (size_t)grow * DD + colBase + sc * 8) = lv;
            }
        }
    } else {
#pragma unroll
        for (int m = 0; m < 2; ++m) {
            int growb = rowBase + mo + m * 16 + crq;
#pragma unroll
            for (int n = 0; n < 2; ++n) {
                int gcol = colBase + no + n * 16 + ccol;
#pragma unroll
                for (int r = 0; r < 4; ++r) {
                    int grow = growb + r;
                    if (grow < M) C[(size_t)grow * DD + gcol] = acc[m][n][r];
                }
            }
        }
    }
}

// ---------------- per-node attention dots (reads fp32 hw) ----------------

__global__ __launch_bounds__(256) void dots_k(const float* __restrict__ hw,
                                              const float* __restrict__ asrc,
                                              const float* __restrict__ adst,
                                              float* __restrict__ es, float* __restrict__ ed) {
    int wave = threadIdx.x >> 6;
    int lane = threadIdx.x & 63;
    int node = blockIdx.x * 4 + wave;
    if (node >= NNODES) return;
    float4 v = *(const float4*)(hw + (size_t)node * DD + lane * 4);
    float4 a = *(const float4*)(asrc + lane * 4);
    float4 b = *(const float4*)(adst + lane * 4);
    float s = v.x * a.x + v.y * a.y + v.z * a.z + v.w * a.w;
    float d = v.x * b.x + v.y * b.y + v.z * b.z + v.w * b.w;
#pragma unroll
    for (int off = 32; off; off >>= 1) {
        s += __shfl_xor(s, off);
        d += __shfl_xor(d, off);
    }
    if (lane == 0) { es[node] = s; ed[node] = d; }
}

// ---------------- fused segment softmax + aggregation; writes fp16 hi/lo split ----
// 2-deep 8-row double-buffered gather pipeline (va/vb reg sets) with
// sched_barrier(0) pinning next-batch load issue ahead of current FMAs.
// Pad lanes gather row 0 with weight exactly 0 -> no tail code.

template<bool RELU>
__global__ __launch_bounds__(256, 4) void gat_agg_k(const float* __restrict__ hw,
                                                    const float* __restrict__ es,
                                                    const float* __restrict__ ed,
                                                    const int* __restrict__ rowptr,
                                                    const int* __restrict__ colsrc,
                                                    float* __restrict__ ealpha,
                                                    const float* __restrict__ bias,
                                                    _Float16* __restrict__ hh,
                                                    _Float16* __restrict__ hl) {
    int wave = threadIdx.x >> 6;
    int lane = threadIdx.x & 63;
    int node = blockIdx.x * 4 + wave;
    if (node >= NNODES) return;
    int start = rowptr[node], end = rowptr[node + 1];
    int deg = end - start;
    float edd = ed[node];

    float4 acc0 = make_float4(0.f, 0.f, 0.f, 0.f);
    float4 acc1 = acc0, acc2 = acc0, acc3 = acc0;

#define FMA4(ACC, W_, V) \
    ACC.x = fmaf(W_, V.x, ACC.x); ACC.y = fmaf(W_, V.y, ACC.y); \
    ACC.z = fmaf(W_, V.z, ACC.z); ACC.w = fmaf(W_, V.w, ACC.w);

    if (deg > 0 && deg <= 64) {
        bool valid = lane < deg;
        int msrc = valid ? colsrc[start + lane] : 0;
        float e = valid ? es[msrc] + edd : -INFINITY;
        e = fmaxf(e, NEG_SLOPE * e);
        float mx = e;
#pragma unroll
        for (int off = 32; off; off >>= 1) mx = fmaxf(mx, __shfl_xor(mx, off));
        float ee = valid ? expf(e - mx) : 0.f;
        float sum = ee;
#pragma unroll
        for (int off = 32; off; off >>= 1) sum += __shfl_xor(sum, off);
        float w = ee / sum;   // exactly 0 for pad lanes

#define FETCH8(V, W_, JB) \
        _Pragma("unroll") \
        for (int q = 0; q < 8; ++q) { \
            int sq = __shfl(msrc, (JB) + q); \
            W_[q] = __shfl(w, (JB) + q); \
            V[q] = *(const float4*)(hw + (size_t)sq * DD + lane * 4); \
        }

#define FMA8(V, W_) \
        FMA4(acc0, W_[0], V[0]); FMA4(acc1, W_[1], V[1]); \
        FMA4(acc2, W_[2], V[2]); FMA4(acc3, W_[3], V[3]); \
        FMA4(acc0, W_[4], V[4]); FMA4(acc1, W_[5], V[5]); \
        FMA4(acc2, W_[6], V[6]); FMA4(acc3, W_[7], V[7]);

        float4 va[8], vb[8];
        float wa[8], wb[8];
        FETCH8(va, wa, 0);
        int jb = 8;
        for (;;) {
            if (jb >= deg) { FMA8(va, wa); break; }
            FETCH8(vb, wb, jb); jb += 8;
            __builtin_amdgcn_sched_barrier(0);   // pin: vb loads issued before va FMAs
            FMA8(va, wa);
            if (jb >= deg) { FMA8(vb, wb); break; }
            FETCH8(va, wa, jb); jb += 8;
            __builtin_amdgcn_sched_barrier(0);
            FMA8(vb, wb);
        }
#undef FETCH8
#undef FMA8
    } else if (deg > 64) {
        float mx = -INFINITY;
        for (int j = start + lane; j < end; j += 64) {
            float e = es[colsrc[j]] + edd;
            e = fmaxf(e, NEG_SLOPE * e);
            mx = fmaxf(mx, e);
        }
#pragma unroll
        for (int off = 32; off; off >>= 1) mx = fmaxf(mx, __shfl_xor(mx, off));
        float sum = 0.f;
        for (int j = start + lane; j < end; j += 64) {
            float e = es[colsrc[j]] + edd;
            e = fmaxf(e, NEG_SLOPE * e);
            float ee = expf(e - mx);
            ealpha[j] = ee;
            sum += ee;
        }
#pragma unroll
        for (int off = 32; off; off >>= 1) sum += __shfl_xor(sum, off);
        float inv = 1.f / sum;
        int j = start;
        for (; j + 4 <= end; j += 4) {
            int s0 = colsrc[j], s1 = colsrc[j + 1], s2 = colsrc[j + 2], s3 = colsrc[j + 3];
            float w0 = ealpha[j] * inv, w1 = ealpha[j + 1] * inv;
            float w2 = ealpha[j + 2] * inv, w3 = ealpha[j + 3] * inv;
            float4 v0 = *(const float4*)(hw + (size_t)s0 * DD + lane * 4);
            float4 v1 = *(const float4*)(hw + (size_t)s1 * DD + lane * 4);
            float4 v2 = *(const float4*)(hw + (size_t)s2 * DD + lane * 4);
            float4 v3 = *(const float4*)(hw + (size_t)s3 * DD + lane * 4);
            FMA4(acc0, w0, v0); FMA4(acc1, w1, v1);
            FMA4(acc2, w2, v2); FMA4(acc3, w3, v3);
        }
        for (; j < end; ++j) {
            int s0 = colsrc[j];
            float w0 = ealpha[j] * inv;
            float4 v0 = *(const float4*)(hw + (size_t)s0 * DD + lane * 4);
            FMA4(acc0, w0, v0);
        }
    }
#undef FMA4

    acc0.x += acc1.x; acc0.y += acc1.y; acc0.z += acc1.z; acc0.w += acc1.w;
    acc2.x += acc3.x; acc2.y += acc3.y; acc2.z += acc3.z; acc2.w += acc3.w;
    acc0.x += acc2.x; acc0.y += acc2.y; acc0.z += acc2.z; acc0.w += acc2.w;
    float4 b4 = *(const float4*)(bias + lane * 4);
    acc0.x += b4.x; acc0.y += b4.y; acc0.z += b4.z; acc0.w += b4.w;
    if (RELU) {
        acc0.x = fmaxf(acc0.x, 0.f); acc0.y = fmaxf(acc0.y, 0.f);
        acc0.z = fmaxf(acc0.z, 0.f); acc0.w = fmaxf(acc0.w, 0.f);
    }
    size_t base = (size_t)node * DD + lane * 4;
    _Float16 h0 = (_Float16)acc0.x, h1 = (_Float16)acc0.y;
    _Float16 h2 = (_Float16)acc0.z, h3 = (_Float16)acc0.w;
    half4 hv; hv[0] = h0; hv[1] = h1; hv[2] = h2; hv[3] = h3;
    half4 lv;
    lv[0] = (_Float16)(acc0.x - (float)h0); lv[1] = (_Float16)(acc0.y - (float)h1);
    lv[2] = (_Float16)(acc0.z - (float)h2); lv[3] = (_Float16)(acc0.w - (float)h3);
    *(half4*)(hh + base) = hv;
    *(half4*)(hl + base) = lv;
}

// ---------------- driver ----------------

extern "C" void kernel_launch(void* const* d_in, const int* in_sizes, int n_in,
                              void* d_out, int out_size, void* d_ws, size_t ws_size,
                              hipStream_t stream) {
    const float* x     = (const float*)d_in[0];
    const int*   ei    = (const int*)d_in[1];     // [2,E]: src then dst
    const float* W1    = (const float*)d_in[2];
    const float* W2    = (const float*)d_in[3];
    const float* Ws    = (const float*)d_in[4];   // [6,256,256]
    const float* a_src = (const float*)d_in[5];
    const float* a_dst = (const float*)d_in[6];
    const float* bias  = (const float*)d_in[7];
    const float* W3    = (const float*)d_in[8];   // [512,256]
    float* out = (float*)d_out;

    const int* src = ei;
    const int* dst = ei + EEDGES;

    const size_t ND = (size_t)NNODES * DD;

    // workspace carve-up
    float* bufA   = (float*)d_ws;            // ND fp32 (hw)
    float* es     = bufA + ND;               // N
    float* edv    = es + NNODES;             // N
    float* ealpha = edv + NNODES;            // E
    int*   rowptr = (int*)(ealpha + EEDGES); // N+1
    int*   cursor = rowptr + (NNODES + 1);   // N
    int*   colsrc = cursor + NNODES;         // E
    int*   bsums  = colsrc + EEDGES;         // SCAN_BLOCKS
    _Float16* P0h = (_Float16*)(((uintptr_t)(bsums + SCAN_BLOCKS) + 15) & ~(uintptr_t)15);
    _Float16* P0l = P0h + ND;
    _Float16* P1h = P0l + ND;
    _Float16* P1l = P1h + ND;
    _Float16* WT  = P1l + ND;                // 9 weight pairs (transposed split)
    const size_t WSZ = (size_t)DD * DD;      // 65536

    // --- CSR build ---
    zero_ints_k<<<(NNODES + 1 + 255) / 256, 256, 0, stream>>>(rowptr, NNODES + 1);
    hist_k<<<(EEDGES + 255) / 256, 256, 0, stream>>>(dst, rowptr);
    scan1_k<<<SCAN_BLOCKS, 256, 0, stream>>>(rowptr, bsums);
    scan2_k<<<1, 128, 0, stream>>>(bsums);
    scan3_k<<<SCAN_BLOCKS, 256, 0, stream>>>(rowptr, bsums, cursor);
    scatter_k<<<(EEDGES + 255) / 256, 256, 0, stream>>>(src, dst, cursor, colsrc);

    // --- weight conversion (transpose + fp16 split) ---
    const int WBLK = (DD * DD + 255) / 256;
    cvt_w_k<false><<<WBLK, 256, 0, stream>>>(W1, WT + 0 * 2 * WSZ, WT + 0 * 2 * WSZ + WSZ);
    cvt_w_k<false><<<WBLK, 256, 0, stream>>>(W2, WT + 1 * 2 * WSZ, WT + 1 * 2 * WSZ + WSZ);
    for (int l = 0; l < 6; ++l)
        cvt_w_k<false><<<WBLK, 256, 0, stream>>>(Ws + (size_t)l * WSZ,
                                                 WT + (2 + l) * 2 * WSZ,
                                                 WT + (2 + l) * 2 * WSZ + WSZ);
    cvt_w_k<true><<<WBLK, 256, 0, stream>>>(W3, WT + 8 * 2 * WSZ, WT + 8 * 2 * WSZ + WSZ);

    // --- x split ---
    cvt_split_k<<<(int)((ND + 255) / 256), 256, 0, stream>>>(x, P0h, P0l, (int)ND);

    dim3 gg(DD / 128, (NNODES + 63) / 64);   // (2, 313) = 626 blocks
    const int nodeBlocks = (NNODES + 3) / 4;

#define WTH(i) (WT + (i) * 2 * WSZ)
#define WTL(i) (WT + (i) * 2 * WSZ + WSZ)

    // t = x@W1 (split out), h0 = t@W2 (split out)
    gemm_k<true><<<gg, 512, 0, stream>>>(P0h, P0l, WTH(0), WTL(0), nullptr, P1h, P1l, NNODES);
    gemm_k<true><<<gg, 512, 0, stream>>>(P1h, P1l, WTH(1), WTL(1), nullptr, P0h, P0l, NNODES);

    // 6 GAT layers: h (P0 split) -> hw (bufA fp32) -> agg -> h (P0 split)
    for (int l = 0; l < 6; ++l) {
        gemm_k<false><<<gg, 512, 0, stream>>>(P0h, P0l, WTH(2 + l), WTL(2 + l),
                                              bufA, nullptr, nullptr, NNODES);
        dots_k<<<nodeBlocks, 256, 0, stream>>>(bufA, a_src + (size_t)l * DD,
                                               a_dst + (size_t)l * DD, es, edv);
        if (l < 5)
            gat_agg_k<false><<<nodeBlocks, 256, 0, stream>>>(bufA, es, edv, rowptr, colsrc,
                                                             ealpha, bias + (size_t)l * DD,
                                                             P0h, P0l);
        else
            gat_agg_k<true><<<nodeBlocks, 256, 0, stream>>>(bufA, es, edv, rowptr, colsrc,
                                                            ealpha, bias + (size_t)l * DD,
                                                            P0h, P0l);
    }

    // out = relu(h) @ (W3_top + W3_bot)  (relu already applied in layer-5 agg)
    gemm_k<false><<<gg, 512, 0, stream>>>(P0h, P0l, WTH(8), WTL(8), out,
                                          nullptr, nullptr, NNODES);
#undef WTH
#undef WTL
}

// Round 3
// 641.270 us; speedup vs baseline: 1.5450x; 1.0583x over previous
//
#include <hip/hip_runtime.h>
#include <hip/hip_fp16.h>
#include <stdint.h>

#define NNODES 20000
#define EEDGES 320000
#define DD     256
#define NEG_SLOPE 0.2f
#define SCAN_BLOCKS ((NNODES + 255) / 256)
#define ESTR   20480   // padded stride for es/ed partial arrays

typedef _Float16 half8 __attribute__((ext_vector_type(8)));
typedef _Float16 half4 __attribute__((ext_vector_type(4)));
typedef float f32x4 __attribute__((ext_vector_type(4)));

// ---------------- CSR build ----------------

__global__ void zero_ints_k(int* __restrict__ p, int n) {
    int i = blockIdx.x * 256 + threadIdx.x;
    if (i < n) p[i] = 0;
}

__global__ void hist_k(const int* __restrict__ dst, int* __restrict__ rowptr) {
    int i = blockIdx.x * 256 + threadIdx.x;
    if (i < EEDGES) atomicAdd(&rowptr[dst[i] + 1], 1);
}

__global__ __launch_bounds__(256) void scan1_k(int* __restrict__ rowptr, int* __restrict__ bsums) {
    __shared__ int buf[256];
    int idx = blockIdx.x * 256 + threadIdx.x;
    int v = (idx < NNODES) ? rowptr[idx + 1] : 0;
    buf[threadIdx.x] = v;
    __syncthreads();
#pragma unroll
    for (int off = 1; off < 256; off <<= 1) {
        int t = (threadIdx.x >= (unsigned)off) ? buf[threadIdx.x - off] : 0;
        __syncthreads();
        buf[threadIdx.x] += t;
        __syncthreads();
    }
    if (idx < NNODES) rowptr[idx + 1] = buf[threadIdx.x];
    if (threadIdx.x == 255) bsums[blockIdx.x] = buf[255];
}

__global__ __launch_bounds__(128) void scan2_k(int* __restrict__ bsums) {
    __shared__ int buf[128];
    int v = (threadIdx.x < SCAN_BLOCKS) ? bsums[threadIdx.x] : 0;
    buf[threadIdx.x] = v;
    __syncthreads();
#pragma unroll
    for (int off = 1; off < 128; off <<= 1) {
        int t = (threadIdx.x >= (unsigned)off) ? buf[threadIdx.x - off] : 0;
        __syncthreads();
        buf[threadIdx.x] += t;
        __syncthreads();
    }
    if (threadIdx.x < SCAN_BLOCKS) bsums[threadIdx.x] = buf[threadIdx.x];
}

__global__ void scan3_k(int* __restrict__ rowptr, const int* __restrict__ bsums,
                        int* __restrict__ cursor) {
    int idx = blockIdx.x * 256 + threadIdx.x;
    if (idx < NNODES) {
        int v = rowptr[idx + 1];
        if (blockIdx.x > 0) { v += bsums[blockIdx.x - 1]; rowptr[idx + 1] = v; }
        if (idx + 1 < NNODES) cursor[idx + 1] = v;
        if (idx == 0) cursor[0] = 0;
    }
}

__global__ void scatter_k(const int* __restrict__ src, const int* __restrict__ dst,
                          int* __restrict__ cursor, int* __restrict__ colsrc) {
    int i = blockIdx.x * 256 + threadIdx.x;
    if (i < EEDGES) {
        int d = dst[i];
        int pos = atomicAdd(&cursor[d], 1);
        colsrc[pos] = src[i];
    }
}

// ---------------- fp32 -> fp16 hi/lo split (row-major, for A side) ----------------

__global__ void cvt_split_k(const float* __restrict__ X, _Float16* __restrict__ Xh,
                            _Float16* __restrict__ Xl, int n) {
    int i = blockIdx.x * 256 + threadIdx.x;
    if (i < n) {
        float v = X[i];
        _Float16 hi = (_Float16)v;
        Xh[i] = hi;
        Xl[i] = (_Float16)(v - (float)hi);
    }
}

// ---------------- weight: W[K][N] fp32 -> W^T hi/lo [N][K] fp16 (optional W3 fold) ----

template<bool SUM>
__global__ void cvt_w_k(const float* __restrict__ W, _Float16* __restrict__ Wh,
                        _Float16* __restrict__ Wl) {
    int i = blockIdx.x * 256 + threadIdx.x;   // over 65536
    if (i < DD * DD) {
        int k = i >> 8, n = i & 255;
        float v = W[i];
        if (SUM) v += W[i + DD * DD];
        _Float16 hi = (_Float16)v;
        Wh[n * DD + k] = hi;
        Wl[n * DD + k] = (_Float16)(v - (float)hi);
    }
}

// ---------------- split-fp16 MFMA GEMM, 64x128 tile, 512 threads ----------------
// R2-proven shape: grid 2x313 = 626 blocks x 8 waves, LDS 48KB, reg-prefetch
// staging, XOR swizzle (slot ^ row&7) on LDS write+read (2-way = free).
// NEW (R3): DOTS epilogue — acc regs ARE hw, so compute the es/ed attention
// dots here (2 mults/lane + 4 shfl_xor within 16-lane col groups + LDS
// cross-wave combine), store per-col-block partials es0/es1, ed0/ed1 (plain
// stores, no atomics, no zeroing). Kills the 6 dots_k dispatches.

template<bool OUT_SPLIT, bool DOTS>
__global__ __launch_bounds__(512, 4) void gemm_k(
    const _Float16* __restrict__ Ah, const _Float16* __restrict__ Al,
    const _Float16* __restrict__ Bh, const _Float16* __restrict__ Bl,
    float* __restrict__ C, _Float16* __restrict__ Ch, _Float16* __restrict__ Cl,
    const float* __restrict__ asrc, const float* __restrict__ adst,
    float* __restrict__ esp, float* __restrict__ edp, int M)
{
    // carve-up (halves): A_h 0..4096, A_l 4096..8192, B_h 8192..16384, B_l 16384..24576
    __shared__ _Float16 smem[24576];
    _Float16* sAh = smem;
    _Float16* sAl = smem + 4096;
    _Float16* sBh = smem + 8192;
    _Float16* sBl = smem + 16384;

    const int t = threadIdx.x;          // 0..511
    const int lane = t & 63;
    const int w = t >> 6;               // 0..7
    const int rowBase = blockIdx.y * 64;
    const int colBase = blockIdx.x * 128;
    const int mo = (w & 1) * 32;        // wave row offset (2 row-waves)
    const int no = (w >> 1) * 32;       // wave col offset (4 col-waves)

    const int arow = t >> 3;            // 0..63
    const int slot = t & 7;             // 0..7 (16B slots per 64-half row)
    const int swz = (slot ^ (arow & 7)) << 3;   // swizzled half-offset within row

    f32x4 acc[2][2];
#pragma unroll
    for (int m = 0; m < 2; ++m)
#pragma unroll
        for (int n = 0; n < 2; ++n) acc[m][n] = (f32x4){0.f, 0.f, 0.f, 0.f};

    int4 pa_h, pa_l, pb_h0, pb_h1, pb_l0, pb_l1;

#define LOADSTAGE(S) { \
        size_t aoff  = (size_t)(rowBase + arow) * DD + (S) * 64 + slot * 8; \
        size_t boff0 = (size_t)(colBase + arow) * DD + (S) * 64 + slot * 8; \
        size_t boff1 = boff0 + (size_t)64 * DD; \
        pa_h  = *(const int4*)(Ah + aoff); \
        pa_l  = *(const int4*)(Al + aoff); \
        pb_h0 = *(const int4*)(Bh + boff0); \
        pb_h1 = *(const int4*)(Bh + boff1); \
        pb_l0 = *(const int4*)(Bl + boff0); \
        pb_l1 = *(const int4*)(Bl + boff1); \
    }

#define WRITESTAGE() { \
        int da  = arow * 64 + swz; \
        *(int4*)(sAh + da) = pa_h; \
        *(int4*)(sAl + da) = pa_l; \
        *(int4*)(sBh + da) = pb_h0; \
        *(int4*)(sBh + da + 4096) = pb_h1; \
        *(int4*)(sBl + da) = pb_l0; \
        *(int4*)(sBl + da + 4096) = pb_l1; \
    }

    LOADSTAGE(0);
    const int fr = lane & 15;
    const int fq = lane >> 4;

    for (int s = 0; s < 4; ++s) {
        __syncthreads();
        WRITESTAGE();
        __syncthreads();
        if (s < 3) { LOADSTAGE(s + 1); }

#pragma unroll
        for (int kk = 0; kk < 2; ++kk) {
            const int c = kk * 4 + fq;
            half8 ah[2], al[2], bh[2], bl[2];
#pragma unroll
            for (int m = 0; m < 2; ++m) {
                int ra = mo + m * 16 + fr;
                int oa = ra * 64 + ((c ^ (ra & 7)) << 3);
                ah[m] = *(const half8*)(sAh + oa);
                al[m] = *(const half8*)(sAl + oa);
            }
#pragma unroll
            for (int n = 0; n < 2; ++n) {
                int rb = no + n * 16 + fr;
                int ob = rb * 64 + ((c ^ (rb & 7)) << 3);
                bh[n] = *(const half8*)(sBh + ob);
                bl[n] = *(const half8*)(sBl + ob);
            }
#pragma unroll
            for (int m = 0; m < 2; ++m)
#pragma unroll
                for (int n = 0; n < 2; ++n) {
                    acc[m][n] = __builtin_amdgcn_mfma_f32_16x16x32_f16(ah[m], bh[n], acc[m][n], 0, 0, 0);
                    acc[m][n] = __builtin_amdgcn_mfma_f32_16x16x32_f16(ah[m], bl[n], acc[m][n], 0, 0, 0);
                    acc[m][n] = __builtin_amdgcn_mfma_f32_16x16x32_f16(al[m], bh[n], acc[m][n], 0, 0, 0);
                    acc[m][n] = __builtin_amdgcn_mfma_f32_16x16x32_f16(al[m], bl[n], acc[m][n], 0, 0, 0);
                }
        }
    }
#undef LOADSTAGE
#undef WRITESTAGE

    // C/D layout (verified): col = lane&15, row = (lane>>4)*4 + reg
    const int ccol = lane & 15;
    const int crq = (lane >> 4) * 4;

    if constexpr (OUT_SPLIT) {
        // bounce via LDS: pitch 136 halves -> coalesced half8 stores
        __syncthreads();   // all staged-LDS reads done before overwrite
#pragma unroll
        for (int m = 0; m < 2; ++m)
#pragma unroll
            for (int n = 0; n < 2; ++n)
#pragma unroll
                for (int r = 0; r < 4; ++r) {
                    int row = mo + m * 16 + crq + r;        // 0..63
                    int col = no + n * 16 + ccol;           // 0..127
                    float v = acc[m][n][r];
                    _Float16 hi = (_Float16)v;
                    smem[row * 136 + col] = hi;
                    smem[8704 + row * 136 + col] = (_Float16)(v - (float)hi);
                }
        __syncthreads();
#pragma unroll
        for (int i = 0; i < 2; ++i) {
            int slotId = i * 512 + t;         // 0..1023
            int srow = slotId >> 4;           // 0..63
            int sc = slotId & 15;             // 16B chunk within 128-half row
            int grow = rowBase + srow;
            if (grow < M) {
                half8 hv = *(const half8*)(smem + srow * 136 + sc * 8);
                half8 lv = *(const half8*)(smem + 8704 + srow * 136 + sc * 8);
                *(half8*)(Ch + (size_t)grow * DD + colBase + sc * 8) = hv;
                *(half8*)(Cl + (size_t)grow * DD + colBase + sc * 8) = lv;
            }
        }
    } else {
#pragma unroll
        for (int m = 0; m < 2; ++m) {
            int growb = rowBase + mo + m * 16 + crq;
#pragma unroll
            for (int n = 0; n < 2; ++n) {
                int gcol = colBase + no + n * 16 + ccol;
#pragma unroll
                for (int r = 0; r < 4; ++r) {
                    int grow = growb + r;
                    if (grow < M) C[(size_t)grow * DD + gcol] = acc[m][n][r];
                }
            }
        }
    }

    if constexpr (DOTS) {
        // attention dots from live accumulators; per-col-block partial rows
        float as0 = asrc[colBase + no + ccol];
        float as1 = asrc[colBase + no + 16 + ccol];
        float ad0 = adst[colBase + no + ccol];
        float ad1 = adst[colBase + no + 16 + ccol];
        __syncthreads();   // staged-LDS reads complete before scratch reuse
        float* sred = (float*)smem;          // [64][8] es + [64][8] ed = 4KB
        const int cw = w >> 1;               // col-wave 0..3
#pragma unroll
        for (int m = 0; m < 2; ++m)
#pragma unroll
            for (int r = 0; r < 4; ++r) {
                float ps = acc[m][0][r] * as0 + acc[m][1][r] * as1;
                float pd = acc[m][0][r] * ad0 + acc[m][1][r] * ad1;
#pragma unroll
                for (int off = 1; off < 16; off <<= 1) {
                    ps += __shfl_xor(ps, off);
                    pd += __shfl_xor(pd, off);
                }
                if (ccol == 0) {
                    int row = mo + m * 16 + crq + r;   // 0..63
                    sred[row * 8 + cw] = ps;
                    sred[512 + row * 8 + cw] = pd;
                }
            }
        __syncthreads();
        if (t < 64) {
            float esb = sred[t * 8 + 0] + sred[t * 8 + 1] + sred[t * 8 + 2] + sred[t * 8 + 3];
            float edb = sred[512 + t * 8 + 0] + sred[512 + t * 8 + 1]
                      + sred[512 + t * 8 + 2] + sred[512 + t * 8 + 3];
            int grow = rowBase + t;
            if (grow < M) {
                esp[(size_t)blockIdx.x * ESTR + grow] = esb;
                edp[(size_t)blockIdx.x * ESTR + grow] = edb;
            }
        }
    }
}

// ---------------- fused segment softmax + aggregation; writes fp16 hi/lo split ----
// R3: pipeline (va/vb double-buffer + sched_barrier pin) applied ONLY to full
// 8-batches; exact tail (4-wide + singles, R0-proven). No pad loads, no
// min-waves clamp — R2 showed pads+clamp cost +67MB traffic and 25% occupancy.

template<bool RELU>
__global__ __launch_bounds__(256) void gat_agg_k(const float* __restrict__ hw,
                                                 const float* __restrict__ es0,
                                                 const float* __restrict__ es1,
                                                 const float* __restrict__ ed0,
                                                 const float* __restrict__ ed1,
                                                 const int* __restrict__ rowptr,
                                                 const int* __restrict__ colsrc,
                                                 float* __restrict__ ealpha,
                                                 const float* __restrict__ bias,
                                                 _Float16* __restrict__ hh,
                                                 _Float16* __restrict__ hl) {
    int wave = threadIdx.x >> 6;
    int lane = threadIdx.x & 63;
    int node = blockIdx.x * 4 + wave;
    if (node >= NNODES) return;
    int start = rowptr[node], end = rowptr[node + 1];
    int deg = end - start;
    float edd = ed0[node] + ed1[node];

    float4 acc0 = make_float4(0.f, 0.f, 0.f, 0.f);
    float4 acc1 = acc0, acc2 = acc0, acc3 = acc0;

#define FMA4(ACC, W_, V) \
    ACC.x = fmaf(W_, V.x, ACC.x); ACC.y = fmaf(W_, V.y, ACC.y); \
    ACC.z = fmaf(W_, V.z, ACC.z); ACC.w = fmaf(W_, V.w, ACC.w);

    if (deg > 0 && deg <= 64) {
        bool valid = lane < deg;
        int msrc = valid ? colsrc[start + lane] : 0;
        float e = valid ? es0[msrc] + es1[msrc] + edd : -INFINITY;
        e = fmaxf(e, NEG_SLOPE * e);
        float mx = e;
#pragma unroll
        for (int off = 32; off; off >>= 1) mx = fmaxf(mx, __shfl_xor(mx, off));
        float ee = valid ? expf(e - mx) : 0.f;
        float sum = ee;
#pragma unroll
        for (int off = 32; off; off >>= 1) sum += __shfl_xor(sum, off);
        float w = ee / sum;

#define FETCH8(V, W_, JB) \
        _Pragma("unroll") \
        for (int q = 0; q < 8; ++q) { \
            int sq = __shfl(msrc, (JB) + q); \
            W_[q] = __shfl(w, (JB) + q); \
            V[q] = *(const float4*)(hw + (size_t)sq * DD + lane * 4); \
        }

#define FMA8(V, W_) \
        FMA4(acc0, W_[0], V[0]); FMA4(acc1, W_[1], V[1]); \
        FMA4(acc2, W_[2], V[2]); FMA4(acc3, W_[3], V[3]); \
        FMA4(acc0, W_[4], V[4]); FMA4(acc1, W_[5], V[5]); \
        FMA4(acc2, W_[6], V[6]); FMA4(acc3, W_[7], V[7]);

        const int nfull = deg & ~7;
        if (nfull > 0) {
            float4 va[8], vb[8];
            float wa[8], wb[8];
            FETCH8(va, wa, 0);
            int jb = 8;
            for (;;) {
                if (jb >= nfull) { FMA8(va, wa); break; }
                FETCH8(vb, wb, jb); jb += 8;
                __builtin_amdgcn_sched_barrier(0);   // pin: vb loads before va FMAs
                FMA8(va, wa);
                if (jb >= nfull) { FMA8(vb, wb); break; }
                FETCH8(va, wa, jb); jb += 8;
                __builtin_amdgcn_sched_barrier(0);
                FMA8(vb, wb);
            }
        }
        int j2 = nfull;
        if (j2 + 4 <= deg) {
            int s0 = __shfl(msrc, j2 + 0), s1 = __shfl(msrc, j2 + 1);
            int s2 = __shfl(msrc, j2 + 2), s3 = __shfl(msrc, j2 + 3);
            float w0 = __shfl(w, j2 + 0), w1 = __shfl(w, j2 + 1);
            float w2 = __shfl(w, j2 + 2), w3 = __shfl(w, j2 + 3);
            float4 v0 = *(const float4*)(hw + (size_t)s0 * DD + lane * 4);
            float4 v1 = *(const float4*)(hw + (size_t)s1 * DD + lane * 4);
            float4 v2 = *(const float4*)(hw + (size_t)s2 * DD + lane * 4);
            float4 v3 = *(const float4*)(hw + (size_t)s3 * DD + lane * 4);
            FMA4(acc0, w0, v0); FMA4(acc1, w1, v1);
            FMA4(acc2, w2, v2); FMA4(acc3, w3, v3);
            j2 += 4;
        }
        for (; j2 < deg; ++j2) {
            int   s0 = __shfl(msrc, j2);
            float w0 = __shfl(w, j2);
            float4 v0 = *(const float4*)(hw + (size_t)s0 * DD + lane * 4);
            FMA4(acc0, w0, v0);
        }
#undef FETCH8
#undef FMA8
    } else if (deg > 64) {
        float mx = -INFINITY;
        for (int j = start + lane; j < end; j += 64) {
            int s = colsrc[j];
            float e = es0[s] + es1[s] + edd;
            e = fmaxf(e, NEG_SLOPE * e);
            mx = fmaxf(mx, e);
        }
#pragma unroll
        for (int off = 32; off; off >>= 1) mx = fmaxf(mx, __shfl_xor(mx, off));
        float sum = 0.f;
        for (int j = start + lane; j < end; j += 64) {
            int s = colsrc[j];
            float e = es0[s] + es1[s] + edd;
            e = fmaxf(e, NEG_SLOPE * e);
            float ee = expf(e - mx);
            ealpha[j] = ee;
            sum += ee;
        }
#pragma unroll
        for (int off = 32; off; off >>= 1) sum += __shfl_xor(sum, off);
        float inv = 1.f / sum;
        int j = start;
        for (; j + 4 <= end; j += 4) {
            int s0 = colsrc[j], s1 = colsrc[j + 1], s2 = colsrc[j + 2], s3 = colsrc[j + 3];
            float w0 = ealpha[j] * inv, w1 = ealpha[j + 1] * inv;
            float w2 = ealpha[j + 2] * inv, w3 = ealpha[j + 3] * inv;
            float4 v0 = *(const float4*)(hw + (size_t)s0 * DD + lane * 4);
            float4 v1 = *(const float4*)(hw + (size_t)s1 * DD + lane * 4);
            float4 v2 = *(const float4*)(hw + (size_t)s2 * DD + lane * 4);
            float4 v3 = *(const float4*)(hw + (size_t)s3 * DD + lane * 4);
            FMA4(acc0, w0, v0); FMA4(acc1, w1, v1);
            FMA4(acc2, w2, v2); FMA4(acc3, w3, v3);
        }
        for (; j < end; ++j) {
            int s0 = colsrc[j];
            float w0 = ealpha[j] * inv;
            float4 v0 = *(const float4*)(hw + (size_t)s0 * DD + lane * 4);
            FMA4(acc0, w0, v0);
        }
    }
#undef FMA4

    acc0.x += acc1.x; acc0.y += acc1.y; acc0.z += acc1.z; acc0.w += acc1.w;
    acc2.x += acc3.x; acc2.y += acc3.y; acc2.z += acc3.z; acc2.w += acc3.w;
    acc0.x += acc2.x; acc0.y += acc2.y; acc0.z += acc2.z; acc0.w += acc2.w;
    float4 b4 = *(const float4*)(bias + lane * 4);
    acc0.x += b4.x; acc0.y += b4.y; acc0.z += b4.z; acc0.w += b4.w;
    if (RELU) {
        acc0.x = fmaxf(acc0.x, 0.f); acc0.y = fmaxf(acc0.y, 0.f);
        acc0.z = fmaxf(acc0.z, 0.f); acc0.w = fmaxf(acc0.w, 0.f);
    }
    size_t base = (size_t)node * DD + lane * 4;
    _Float16 h0 = (_Float16)acc0.x, h1 = (_Float16)acc0.y;
    _Float16 h2 = (_Float16)acc0.z, h3 = (_Float16)acc0.w;
    half4 hv; hv[0] = h0; hv[1] = h1; hv[2] = h2; hv[3] = h3;
    half4 lv;
    lv[0] = (_Float16)(acc0.x - (float)h0); lv[1] = (_Float16)(acc0.y - (float)h1);
    lv[2] = (_Float16)(acc0.z - (float)h2); lv[3] = (_Float16)(acc0.w - (float)h3);
    *(half4*)(hh + base) = hv;
    *(half4*)(hl + base) = lv;
}

// ---------------- driver ----------------

extern "C" void kernel_launch(void* const* d_in, const int* in_sizes, int n_in,
                              void* d_out, int out_size, void* d_ws, size_t ws_size,
                              hipStream_t stream) {
    const float* x     = (const float*)d_in[0];
    const int*   ei    = (const int*)d_in[1];     // [2,E]: src then dst
    const float* W1    = (const float*)d_in[2];
    const float* W2    = (const float*)d_in[3];
    const float* Ws    = (const float*)d_in[4];   // [6,256,256]
    const float* a_src = (const float*)d_in[5];
    const float* a_dst = (const float*)d_in[6];
    const float* bias  = (const float*)d_in[7];
    const float* W3    = (const float*)d_in[8];   // [512,256]
    float* out = (float*)d_out;

    const int* src = ei;
    const int* dst = ei + EEDGES;

    const size_t ND = (size_t)NNODES * DD;

    // workspace carve-up
    float* bufA   = (float*)d_ws;            // ND fp32 (hw)
    float* es01   = bufA + ND;               // 2 * ESTR
    float* ed01   = es01 + 2 * ESTR;         // 2 * ESTR
    float* ealpha = ed01 + 2 * ESTR;         // E
    int*   rowptr = (int*)(ealpha + EEDGES); // N+1
    int*   cursor = rowptr + (NNODES + 1);   // N
    int*   colsrc = cursor + NNODES;         // E
    int*   bsums  = colsrc + EEDGES;         // SCAN_BLOCKS
    _Float16* P0h = (_Float16*)(((uintptr_t)(bsums + SCAN_BLOCKS) + 15) & ~(uintptr_t)15);
    _Float16* P0l = P0h + ND;
    _Float16* P1h = P0l + ND;
    _Float16* P1l = P1h + ND;
    _Float16* WT  = P1l + ND;                // 9 weight pairs (transposed split)
    const size_t WSZ = (size_t)DD * DD;      // 65536

    // --- CSR build ---
    zero_ints_k<<<(NNODES + 1 + 255) / 256, 256, 0, stream>>>(rowptr, NNODES + 1);
    hist_k<<<(EEDGES + 255) / 256, 256, 0, stream>>>(dst, rowptr);
    scan1_k<<<SCAN_BLOCKS, 256, 0, stream>>>(rowptr, bsums);
    scan2_k<<<1, 128, 0, stream>>>(bsums);
    scan3_k<<<SCAN_BLOCKS, 256, 0, stream>>>(rowptr, bsums, cursor);
    scatter_k<<<(EEDGES + 255) / 256, 256, 0, stream>>>(src, dst, cursor, colsrc);

    // --- weight conversion (transpose + fp16 split) ---
    const int WBLK = (DD * DD + 255) / 256;
    cvt_w_k<false><<<WBLK, 256, 0, stream>>>(W1, WT + 0 * 2 * WSZ, WT + 0 * 2 * WSZ + WSZ);
    cvt_w_k<false><<<WBLK, 256, 0, stream>>>(W2, WT + 1 * 2 * WSZ, WT + 1 * 2 * WSZ + WSZ);
    for (int l = 0; l < 6; ++l)
        cvt_w_k<false><<<WBLK, 256, 0, stream>>>(Ws + (size_t)l * WSZ,
                                                 WT + (2 + l) * 2 * WSZ,
                                                 WT + (2 + l) * 2 * WSZ + WSZ);
    cvt_w_k<true><<<WBLK, 256, 0, stream>>>(W3, WT + 8 * 2 * WSZ, WT + 8 * 2 * WSZ + WSZ);

    // --- x split ---
    cvt_split_k<<<(int)((ND + 255) / 256), 256, 0, stream>>>(x, P0h, P0l, (int)ND);

    dim3 gg(DD / 128, (NNODES + 63) / 64);   // (2, 313) = 626 blocks
    const int nodeBlocks = (NNODES + 3) / 4;

#define WTH(i) (WT + (i) * 2 * WSZ)
#define WTL(i) (WT + (i) * 2 * WSZ + WSZ)

    // t = x@W1 (split out), h0 = t@W2 (split out)
    gemm_k<true, false><<<gg, 512, 0, stream>>>(P0h, P0l, WTH(0), WTL(0), nullptr, P1h, P1l,
                                                nullptr, nullptr, nullptr, nullptr, NNODES);
    gemm_k<true, false><<<gg, 512, 0, stream>>>(P1h, P1l, WTH(1), WTL(1), nullptr, P0h, P0l,
                                                nullptr, nullptr, nullptr, nullptr, NNODES);

    // 6 GAT layers: h (P0 split) -> hw (bufA fp32) + fused dots -> agg -> h (P0 split)
    for (int l = 0; l < 6; ++l) {
        gemm_k<false, true><<<gg, 512, 0, stream>>>(P0h, P0l, WTH(2 + l), WTL(2 + l),
                                                    bufA, nullptr, nullptr,
                                                    a_src + (size_t)l * DD, a_dst + (size_t)l * DD,
                                                    es01, ed01, NNODES);
        if (l < 5)
            gat_agg_k<false><<<nodeBlocks, 256, 0, stream>>>(bufA, es01, es01 + ESTR,
                                                             ed01, ed01 + ESTR,
                                                             rowptr, colsrc, ealpha,
                                                             bias + (size_t)l * DD, P0h, P0l);
        else
            gat_agg_k<true><<<nodeBlocks, 256, 0, stream>>>(bufA, es01, es01 + ESTR,
                                                            ed01, ed01 + ESTR,
                                                            rowptr, colsrc, ealpha,
                                                            bias + (size_t)l * DD, P0h, P0l);
    }

    // out = relu(h) @ (W3_top + W3_bot)  (relu already applied in layer-5 agg)
    gemm_k<false, false><<<gg, 512, 0, stream>>>(P0h, P0l, WTH(8), WTL(8), out,
                                                 nullptr, nullptr,
                                                 nullptr, nullptr, nullptr, nullptr, NNODES);
#undef WTH
#undef WTL
}

// Round 4
// 596.252 us; speedup vs baseline: 1.6617x; 1.0755x over previous
//
#include <hip/hip_runtime.h>
#include <hip/hip_fp16.h>
#include <stdint.h>

#define NNODES 20000
#define EEDGES 320000
#define DD     256
#define NEG_SLOPE 0.2f
#define SCAN_BLOCKS ((NNODES + 255) / 256)
#define ESTR   20480   // padded stride for es/ed partial arrays

typedef _Float16 half8 __attribute__((ext_vector_type(8)));
typedef _Float16 half4 __attribute__((ext_vector_type(4)));
typedef float f32x4 __attribute__((ext_vector_type(4)));

// ---------------- CSR build ----------------

__global__ void zero_ints_k(int* __restrict__ p, int n) {
    int i = blockIdx.x * 256 + threadIdx.x;
    if (i < n) p[i] = 0;
}

__global__ void hist_k(const int* __restrict__ dst, int* __restrict__ rowptr) {
    int i = blockIdx.x * 256 + threadIdx.x;
    if (i < EEDGES) atomicAdd(&rowptr[dst[i] + 1], 1);
}

__global__ __launch_bounds__(256) void scan1_k(int* __restrict__ rowptr, int* __restrict__ bsums) {
    __shared__ int buf[256];
    int idx = blockIdx.x * 256 + threadIdx.x;
    int v = (idx < NNODES) ? rowptr[idx + 1] : 0;
    buf[threadIdx.x] = v;
    __syncthreads();
#pragma unroll
    for (int off = 1; off < 256; off <<= 1) {
        int t = (threadIdx.x >= (unsigned)off) ? buf[threadIdx.x - off] : 0;
        __syncthreads();
        buf[threadIdx.x] += t;
        __syncthreads();
    }
    if (idx < NNODES) rowptr[idx + 1] = buf[threadIdx.x];
    if (threadIdx.x == 255) bsums[blockIdx.x] = buf[255];
}

__global__ __launch_bounds__(128) void scan2_k(int* __restrict__ bsums) {
    __shared__ int buf[128];
    int v = (threadIdx.x < SCAN_BLOCKS) ? bsums[threadIdx.x] : 0;
    buf[threadIdx.x] = v;
    __syncthreads();
#pragma unroll
    for (int off = 1; off < 128; off <<= 1) {
        int t = (threadIdx.x >= (unsigned)off) ? buf[threadIdx.x - off] : 0;
        __syncthreads();
        buf[threadIdx.x] += t;
        __syncthreads();
    }
    if (threadIdx.x < SCAN_BLOCKS) bsums[threadIdx.x] = buf[threadIdx.x];
}

__global__ void scan3_k(int* __restrict__ rowptr, const int* __restrict__ bsums,
                        int* __restrict__ cursor) {
    int idx = blockIdx.x * 256 + threadIdx.x;
    if (idx < NNODES) {
        int v = rowptr[idx + 1];
        if (blockIdx.x > 0) { v += bsums[blockIdx.x - 1]; rowptr[idx + 1] = v; }
        if (idx + 1 < NNODES) cursor[idx + 1] = v;
        if (idx == 0) cursor[0] = 0;
    }
}

__global__ void scatter_k(const int* __restrict__ src, const int* __restrict__ dst,
                          int* __restrict__ cursor, int* __restrict__ colsrc) {
    int i = blockIdx.x * 256 + threadIdx.x;
    if (i < EEDGES) {
        int d = dst[i];
        int pos = atomicAdd(&cursor[d], 1);
        colsrc[pos] = src[i];
    }
}

// ---------------- fp32 -> fp16 hi/lo split (row-major) ----------------

__global__ void cvt_split_k(const float* __restrict__ X, _Float16* __restrict__ Xh,
                            _Float16* __restrict__ Xl, int n) {
    int i = blockIdx.x * 256 + threadIdx.x;
    if (i < n) {
        float v = X[i];
        _Float16 hi = (_Float16)v;
        Xh[i] = hi;
        Xl[i] = (_Float16)(v - (float)hi);
    }
}

// ---------------- weight: W[K][N] fp32 -> W^T hi/lo [N][K] fp16 (optional W3 fold) ----

template<bool SUM>
__global__ void cvt_w_k(const float* __restrict__ W, _Float16* __restrict__ Wh,
                        _Float16* __restrict__ Wl) {
    int i = blockIdx.x * 256 + threadIdx.x;   // over 65536
    if (i < DD * DD) {
        int k = i >> 8, n = i & 255;
        float v = W[i];
        if (SUM) v += W[i + DD * DD];
        _Float16 hi = (_Float16)v;
        Wh[n * DD + k] = hi;
        Wl[n * DD + k] = (_Float16)(v - (float)hi);
    }
}

// ---------------- split-fp16 MFMA GEMM, 64x128 tile, 512 threads ----------------
// R2-proven shape: grid 2x313, 8 waves, LDS 48KB, reg-prefetch staging,
// XOR swizzle (slot ^ row&7) on LDS write+read (2-way = free).
// DOTS epilogue (R3-proven): es/ed attention dots from live accumulators,
// per-col-block partials (plain stores, no atomics). Kills dots_k dispatches.
// Also used (R4) with M=256 to fold W12^T = (W1@W2)^T on device: A = W2^T
// split, B^T = W1 row-major split -> C[m][n] = sum_k W2[k][m] W1[n][k]
// = W12^T[m][n], stored split = ready-to-use B operand for x@W12.

template<bool OUT_SPLIT, bool DOTS>
__global__ __launch_bounds__(512, 4) void gemm_k(
    const _Float16* __restrict__ Ah, const _Float16* __restrict__ Al,
    const _Float16* __restrict__ Bh, const _Float16* __restrict__ Bl,
    float* __restrict__ C, _Float16* __restrict__ Ch, _Float16* __restrict__ Cl,
    const float* __restrict__ asrc, const float* __restrict__ adst,
    float* __restrict__ esp, float* __restrict__ edp, int M)
{
    // carve-up (halves): A_h 0..4096, A_l 4096..8192, B_h 8192..16384, B_l 16384..24576
    __shared__ _Float16 smem[24576];
    _Float16* sAh = smem;
    _Float16* sAl = smem + 4096;
    _Float16* sBh = smem + 8192;
    _Float16* sBl = smem + 16384;

    const int t = threadIdx.x;          // 0..511
    const int lane = t & 63;
    const int w = t >> 6;               // 0..7
    const int rowBase = blockIdx.y * 64;
    const int colBase = blockIdx.x * 128;
    const int mo = (w & 1) * 32;        // wave row offset (2 row-waves)
    const int no = (w >> 1) * 32;       // wave col offset (4 col-waves)

    const int arow = t >> 3;            // 0..63
    const int slot = t & 7;             // 0..7 (16B slots per 64-half row)
    const int swz = (slot ^ (arow & 7)) << 3;   // swizzled half-offset within row

    f32x4 acc[2][2];
#pragma unroll
    for (int m = 0; m < 2; ++m)
#pragma unroll
        for (int n = 0; n < 2; ++n) acc[m][n] = (f32x4){0.f, 0.f, 0.f, 0.f};

    int4 pa_h, pa_l, pb_h0, pb_h1, pb_l0, pb_l1;

#define LOADSTAGE(S) { \
        size_t aoff  = (size_t)(rowBase + arow) * DD + (S) * 64 + slot * 8; \
        size_t boff0 = (size_t)(colBase + arow) * DD + (S) * 64 + slot * 8; \
        size_t boff1 = boff0 + (size_t)64 * DD; \
        pa_h  = *(const int4*)(Ah + aoff); \
        pa_l  = *(const int4*)(Al + aoff); \
        pb_h0 = *(const int4*)(Bh + boff0); \
        pb_h1 = *(const int4*)(Bh + boff1); \
        pb_l0 = *(const int4*)(Bl + boff0); \
        pb_l1 = *(const int4*)(Bl + boff1); \
    }

#define WRITESTAGE() { \
        int da  = arow * 64 + swz; \
        *(int4*)(sAh + da) = pa_h; \
        *(int4*)(sAl + da) = pa_l; \
        *(int4*)(sBh + da) = pb_h0; \
        *(int4*)(sBh + da + 4096) = pb_h1; \
        *(int4*)(sBl + da) = pb_l0; \
        *(int4*)(sBl + da + 4096) = pb_l1; \
    }

    LOADSTAGE(0);
    const int fr = lane & 15;
    const int fq = lane >> 4;

    for (int s = 0; s < 4; ++s) {
        __syncthreads();
        WRITESTAGE();
        __syncthreads();
        if (s < 3) { LOADSTAGE(s + 1); }

#pragma unroll
        for (int kk = 0; kk < 2; ++kk) {
            const int c = kk * 4 + fq;
            half8 ah[2], al[2], bh[2], bl[2];
#pragma unroll
            for (int m = 0; m < 2; ++m) {
                int ra = mo + m * 16 + fr;
                int oa = ra * 64 + ((c ^ (ra & 7)) << 3);
                ah[m] = *(const half8*)(sAh + oa);
                al[m] = *(const half8*)(sAl + oa);
            }
#pragma unroll
            for (int n = 0; n < 2; ++n) {
                int rb = no + n * 16 + fr;
                int ob = rb * 64 + ((c ^ (rb & 7)) << 3);
                bh[n] = *(const half8*)(sBh + ob);
                bl[n] = *(const half8*)(sBl + ob);
            }
#pragma unroll
            for (int m = 0; m < 2; ++m)
#pragma unroll
                for (int n = 0; n < 2; ++n) {
                    acc[m][n] = __builtin_amdgcn_mfma_f32_16x16x32_f16(ah[m], bh[n], acc[m][n], 0, 0, 0);
                    acc[m][n] = __builtin_amdgcn_mfma_f32_16x16x32_f16(ah[m], bl[n], acc[m][n], 0, 0, 0);
                    acc[m][n] = __builtin_amdgcn_mfma_f32_16x16x32_f16(al[m], bh[n], acc[m][n], 0, 0, 0);
                    acc[m][n] = __builtin_amdgcn_mfma_f32_16x16x32_f16(al[m], bl[n], acc[m][n], 0, 0, 0);
                }
        }
    }
#undef LOADSTAGE
#undef WRITESTAGE

    // C/D layout (verified): col = lane&15, row = (lane>>4)*4 + reg
    const int ccol = lane & 15;
    const int crq = (lane >> 4) * 4;

    if constexpr (OUT_SPLIT) {
        // bounce via LDS: pitch 136 halves -> coalesced half8 stores
        __syncthreads();   // all staged-LDS reads done before overwrite
#pragma unroll
        for (int m = 0; m < 2; ++m)
#pragma unroll
            for (int n = 0; n < 2; ++n)
#pragma unroll
                for (int r = 0; r < 4; ++r) {
                    int row = mo + m * 16 + crq + r;        // 0..63
                    int col = no + n * 16 + ccol;           // 0..127
                    float v = acc[m][n][r];
                    _Float16 hi = (_Float16)v;
                    smem[row * 136 + col] = hi;
                    smem[8704 + row * 136 + col] = (_Float16)(v - (float)hi);
                }
        __syncthreads();
#pragma unroll
        for (int i = 0; i < 2; ++i) {
            int slotId = i * 512 + t;         // 0..1023
            int srow = slotId >> 4;           // 0..63
            int sc = slotId & 15;             // 16B chunk within 128-half row
            int grow = rowBase + srow;
            if (grow < M) {
                half8 hv = *(const half8*)(smem + srow * 136 + sc * 8);
                half8 lv = *(const half8*)(smem + 8704 + srow * 136 + sc * 8);
                *(half8*)(Ch + (size_t)grow * DD + colBase + sc * 8) = hv;
                *(half8*)(Cl + (size_t)grow * DD + colBase + sc * 8) = lv;
            }
        }
    } else {
#pragma unroll
        for (int m = 0; m < 2; ++m) {
            int growb = rowBase + mo + m * 16 + crq;
#pragma unroll
            for (int n = 0; n < 2; ++n) {
                int gcol = colBase + no + n * 16 + ccol;
#pragma unroll
                for (int r = 0; r < 4; ++r) {
                    int grow = growb + r;
                    if (grow < M) C[(size_t)grow * DD + gcol] = acc[m][n][r];
                }
            }
        }
    }

    if constexpr (DOTS) {
        // attention dots from live accumulators; per-col-block partial rows
        float as0 = asrc[colBase + no + ccol];
        float as1 = asrc[colBase + no + 16 + ccol];
        float ad0 = adst[colBase + no + ccol];
        float ad1 = adst[colBase + no + 16 + ccol];
        __syncthreads();   // staged-LDS reads complete before scratch reuse
        float* sred = (float*)smem;          // [64][8] es + [64][8] ed = 4KB
        const int cw = w >> 1;               // col-wave 0..3
#pragma unroll
        for (int m = 0; m < 2; ++m)
#pragma unroll
            for (int r = 0; r < 4; ++r) {
                float ps = acc[m][0][r] * as0 + acc[m][1][r] * as1;
                float pd = acc[m][0][r] * ad0 + acc[m][1][r] * ad1;
#pragma unroll
                for (int off = 1; off < 16; off <<= 1) {
                    ps += __shfl_xor(ps, off);
                    pd += __shfl_xor(pd, off);
                }
                if (ccol == 0) {
                    int row = mo + m * 16 + crq + r;   // 0..63
                    sred[row * 8 + cw] = ps;
                    sred[512 + row * 8 + cw] = pd;
                }
            }
        __syncthreads();
        if (t < 64) {
            float esb = sred[t * 8 + 0] + sred[t * 8 + 1] + sred[t * 8 + 2] + sred[t * 8 + 3];
            float edb = sred[512 + t * 8 + 0] + sred[512 + t * 8 + 1]
                      + sred[512 + t * 8 + 2] + sred[512 + t * 8 + 3];
            int grow = rowBase + t;
            if (grow < M) {
                esp[(size_t)blockIdx.x * ESTR + grow] = esb;
                edp[(size_t)blockIdx.x * ESTR + grow] = edb;
            }
        }
    }
}

// ---------------- fused segment softmax + aggregation; writes fp16 hi/lo split ----
// R4: EXACT R0-proven gather body (46 us: VGPR 36, Occ 57%) — no explicit
// pipeline, no sched_barrier, no min-waves clamp. R2/R3 A/B showed the
// register pipeline costs occupancy (36->72 VGPR, 57->27% Occ) and loses
// net 5 us/dispatch in this latency-bound regime: TLP > ILP here.
// Only change vs R0: es/ed come from the two col-block partial arrays.

template<bool RELU>
__global__ __launch_bounds__(256) void gat_agg_k(const float* __restrict__ hw,
                                                 const float* __restrict__ es0,
                                                 const float* __restrict__ es1,
                                                 const float* __restrict__ ed0,
                                                 const float* __restrict__ ed1,
                                                 const int* __restrict__ rowptr,
                                                 const int* __restrict__ colsrc,
                                                 float* __restrict__ ealpha,
                                                 const float* __restrict__ bias,
                                                 _Float16* __restrict__ hh,
                                                 _Float16* __restrict__ hl) {
    int wave = threadIdx.x >> 6;
    int lane = threadIdx.x & 63;
    int node = blockIdx.x * 4 + wave;
    if (node >= NNODES) return;
    int start = rowptr[node], end = rowptr[node + 1];
    int deg = end - start;
    float edd = ed0[node] + ed1[node];

    float4 acc0 = make_float4(0.f, 0.f, 0.f, 0.f);
    float4 acc1 = acc0, acc2 = acc0, acc3 = acc0;
    float4 acc4 = acc0, acc5 = acc0, acc6 = acc0, acc7 = acc0;

#define FMA4(ACC, W_, V) \
    ACC.x = fmaf(W_, V.x, ACC.x); ACC.y = fmaf(W_, V.y, ACC.y); \
    ACC.z = fmaf(W_, V.z, ACC.z); ACC.w = fmaf(W_, V.w, ACC.w);

    if (deg <= 64) {
        if (deg > 0) {
            int j = start + lane;
            bool valid = j < end;
            int msrc = valid ? colsrc[j] : 0;
            float e = valid ? es0[msrc] + es1[msrc] + edd : -INFINITY;
            e = fmaxf(e, NEG_SLOPE * e);
            float mx = e;
#pragma unroll
            for (int off = 32; off; off >>= 1) mx = fmaxf(mx, __shfl_xor(mx, off));
            float ee = valid ? expf(e - mx) : 0.f;
            float sum = ee;
#pragma unroll
            for (int off = 32; off; off >>= 1) sum += __shfl_xor(sum, off);
            float w = ee / sum;

            int j2 = 0;
            for (; j2 + 8 <= deg; j2 += 8) {
                int s0 = __shfl(msrc, j2 + 0), s1 = __shfl(msrc, j2 + 1);
                int s2 = __shfl(msrc, j2 + 2), s3 = __shfl(msrc, j2 + 3);
                int s4 = __shfl(msrc, j2 + 4), s5 = __shfl(msrc, j2 + 5);
                int s6 = __shfl(msrc, j2 + 6), s7 = __shfl(msrc, j2 + 7);
                float w0 = __shfl(w, j2 + 0), w1 = __shfl(w, j2 + 1);
                float w2 = __shfl(w, j2 + 2), w3 = __shfl(w, j2 + 3);
                float w4 = __shfl(w, j2 + 4), w5 = __shfl(w, j2 + 5);
                float w6 = __shfl(w, j2 + 6), w7 = __shfl(w, j2 + 7);
                float4 v0 = *(const float4*)(hw + (size_t)s0 * DD + lane * 4);
                float4 v1 = *(const float4*)(hw + (size_t)s1 * DD + lane * 4);
                float4 v2 = *(const float4*)(hw + (size_t)s2 * DD + lane * 4);
                float4 v3 = *(const float4*)(hw + (size_t)s3 * DD + lane * 4);
                float4 v4 = *(const float4*)(hw + (size_t)s4 * DD + lane * 4);
                float4 v5 = *(const float4*)(hw + (size_t)s5 * DD + lane * 4);
                float4 v6 = *(const float4*)(hw + (size_t)s6 * DD + lane * 4);
                float4 v7 = *(const float4*)(hw + (size_t)s7 * DD + lane * 4);
                FMA4(acc0, w0, v0); FMA4(acc1, w1, v1);
                FMA4(acc2, w2, v2); FMA4(acc3, w3, v3);
                FMA4(acc4, w4, v4); FMA4(acc5, w5, v5);
                FMA4(acc6, w6, v6); FMA4(acc7, w7, v7);
            }
            if (j2 + 4 <= deg) {
                int s0 = __shfl(msrc, j2 + 0), s1 = __shfl(msrc, j2 + 1);
                int s2 = __shfl(msrc, j2 + 2), s3 = __shfl(msrc, j2 + 3);
                float w0 = __shfl(w, j2 + 0), w1 = __shfl(w, j2 + 1);
                float w2 = __shfl(w, j2 + 2), w3 = __shfl(w, j2 + 3);
                float4 v0 = *(const float4*)(hw + (size_t)s0 * DD + lane * 4);
                float4 v1 = *(const float4*)(hw + (size_t)s1 * DD + lane * 4);
                float4 v2 = *(const float4*)(hw + (size_t)s2 * DD + lane * 4);
                float4 v3 = *(const float4*)(hw + (size_t)s3 * DD + lane * 4);
                FMA4(acc0, w0, v0); FMA4(acc1, w1, v1);
                FMA4(acc2, w2, v2); FMA4(acc3, w3, v3);
                j2 += 4;
            }
            for (; j2 < deg; ++j2) {
                int   s0 = __shfl(msrc, j2);
                float w0 = __shfl(w, j2);
                float4 v0 = *(const float4*)(hw + (size_t)s0 * DD + lane * 4);
                FMA4(acc0, w0, v0);
            }
        }
    } else {
        float mx = -INFINITY;
        for (int j = start + lane; j < end; j += 64) {
            int s = colsrc[j];
            float e = es0[s] + es1[s] + edd;
            e = fmaxf(e, NEG_SLOPE * e);
            mx = fmaxf(mx, e);
        }
#pragma unroll
        for (int off = 32; off; off >>= 1) mx = fmaxf(mx, __shfl_xor(mx, off));
        float sum = 0.f;
        for (int j = start + lane; j < end; j += 64) {
            int s = colsrc[j];
            float e = es0[s] + es1[s] + edd;
            e = fmaxf(e, NEG_SLOPE * e);
            float ee = expf(e - mx);
            ealpha[j] = ee;
            sum += ee;
        }
#pragma unroll
        for (int off = 32; off; off >>= 1) sum += __shfl_xor(sum, off);
        float inv = 1.f / sum;
        int j = start;
        for (; j + 4 <= end; j += 4) {
            int s0 = colsrc[j], s1 = colsrc[j + 1], s2 = colsrc[j + 2], s3 = colsrc[j + 3];
            float w0 = ealpha[j] * inv, w1 = ealpha[j + 1] * inv;
            float w2 = ealpha[j + 2] * inv, w3 = ealpha[j + 3] * inv;
            float4 v0 = *(const float4*)(hw + (size_t)s0 * DD + lane * 4);
            float4 v1 = *(const float4*)(hw + (size_t)s1 * DD + lane * 4);
            float4 v2 = *(const float4*)(hw + (size_t)s2 * DD + lane * 4);
            float4 v3 = *(const float4*)(hw + (size_t)s3 * DD + lane * 4);
            FMA4(acc0, w0, v0); FMA4(acc1, w1, v1);
            FMA4(acc2, w2, v2); FMA4(acc3, w3, v3);
        }
        for (; j < end; ++j) {
            int s0 = colsrc[j];
            float w0 = ealpha[j] * inv;
            float4 v0 = *(const float4*)(hw + (size_t)s0 * DD + lane * 4);
            FMA4(acc0, w0, v0);
        }
    }
#undef FMA4

    acc0.x += acc4.x; acc0.y += acc4.y; acc0.z += acc4.z; acc0.w += acc4.w;
    acc1.x += acc5.x; acc1.y += acc5.y; acc1.z += acc5.z; acc1.w += acc5.w;
    acc2.x += acc6.x; acc2.y += acc6.y; acc2.z += acc6.z; acc2.w += acc6.w;
    acc3.x += acc7.x; acc3.y += acc7.y; acc3.z += acc7.z; acc3.w += acc7.w;
    acc0.x += acc1.x; acc0.y += acc1.y; acc0.z += acc1.z; acc0.w += acc1.w;
    acc2.x += acc3.x; acc2.y += acc3.y; acc2.z += acc3.z; acc2.w += acc3.w;
    acc0.x += acc2.x; acc0.y += acc2.y; acc0.z += acc2.z; acc0.w += acc2.w;
    float4 b4 = *(const float4*)(bias + lane * 4);
    acc0.x += b4.x; acc0.y += b4.y; acc0.z += b4.z; acc0.w += b4.w;
    if (RELU) {
        acc0.x = fmaxf(acc0.x, 0.f); acc0.y = fmaxf(acc0.y, 0.f);
        acc0.z = fmaxf(acc0.z, 0.f); acc0.w = fmaxf(acc0.w, 0.f);
    }
    size_t base = (size_t)node * DD + lane * 4;
    _Float16 h0 = (_Float16)acc0.x, h1 = (_Float16)acc0.y;
    _Float16 h2 = (_Float16)acc0.z, h3 = (_Float16)acc0.w;
    half4 hv; hv[0] = h0; hv[1] = h1; hv[2] = h2; hv[3] = h3;
    half4 lv;
    lv[0] = (_Float16)(acc0.x - (float)h0); lv[1] = (_Float16)(acc0.y - (float)h1);
    lv[2] = (_Float16)(acc0.z - (float)h2); lv[3] = (_Float16)(acc0.w - (float)h3);
    *(half4*)(hh + base) = hv;
    *(half4*)(hl + base) = lv;
}

// ---------------- driver ----------------

extern "C" void kernel_launch(void* const* d_in, const int* in_sizes, int n_in,
                              void* d_out, int out_size, void* d_ws, size_t ws_size,
                              hipStream_t stream) {
    const float* x     = (const float*)d_in[0];
    const int*   ei    = (const int*)d_in[1];     // [2,E]: src then dst
    const float* W1    = (const float*)d_in[2];
    const float* W2    = (const float*)d_in[3];
    const float* Ws    = (const float*)d_in[4];   // [6,256,256]
    const float* a_src = (const float*)d_in[5];
    const float* a_dst = (const float*)d_in[6];
    const float* bias  = (const float*)d_in[7];
    const float* W3    = (const float*)d_in[8];   // [512,256]
    float* out = (float*)d_out;

    const int* src = ei;
    const int* dst = ei + EEDGES;

    const size_t ND = (size_t)NNODES * DD;

    // workspace carve-up
    float* bufA   = (float*)d_ws;            // ND fp32 (hw)
    float* es01   = bufA + ND;               // 2 * ESTR
    float* ed01   = es01 + 2 * ESTR;         // 2 * ESTR
    float* ealpha = ed01 + 2 * ESTR;         // E
    int*   rowptr = (int*)(ealpha + EEDGES); // N+1
    int*   cursor = rowptr + (NNODES + 1);   // N
    int*   colsrc = cursor + NNODES;         // E
    int*   bsums  = colsrc + EEDGES;         // SCAN_BLOCKS
    _Float16* P0h = (_Float16*)(((uintptr_t)(bsums + SCAN_BLOCKS) + 15) & ~(uintptr_t)15);
    _Float16* P0l = P0h + ND;
    _Float16* P1h = P0l + ND;
    _Float16* P1l = P1h + ND;
    _Float16* WT  = P1l + ND;                // 10 weight pairs (split)
    const size_t WSZ = (size_t)DD * DD;      // 65536

#define WTH(i) (WT + (i) * 2 * WSZ)
#define WTL(i) (WT + (i) * 2 * WSZ + WSZ)

    // --- CSR build ---
    zero_ints_k<<<(NNODES + 1 + 255) / 256, 256, 0, stream>>>(rowptr, NNODES + 1);
    hist_k<<<(EEDGES + 255) / 256, 256, 0, stream>>>(dst, rowptr);
    scan1_k<<<SCAN_BLOCKS, 256, 0, stream>>>(rowptr, bsums);
    scan2_k<<<1, 128, 0, stream>>>(bsums);
    scan3_k<<<SCAN_BLOCKS, 256, 0, stream>>>(rowptr, bsums, cursor);
    scatter_k<<<(EEDGES + 255) / 256, 256, 0, stream>>>(src, dst, cursor, colsrc);

    // --- weight conversion ---
    const int WBLK = (DD * DD + 255) / 256;
    // slot 0: W1 split in ORIGINAL row-major layout (B^T operand for W12 fold)
    cvt_split_k<<<WBLK, 256, 0, stream>>>(W1, WTH(0), WTL(0), DD * DD);
    // slot 1: W2^T split (A operand for W12 fold)
    cvt_w_k<false><<<WBLK, 256, 0, stream>>>(W2, WTH(1), WTL(1));
    for (int l = 0; l < 6; ++l)
        cvt_w_k<false><<<WBLK, 256, 0, stream>>>(Ws + (size_t)l * WSZ, WTH(2 + l), WTL(2 + l));
    cvt_w_k<true><<<WBLK, 256, 0, stream>>>(W3, WTH(8), WTL(8));

    // --- W12^T fold: C[m][n] = sum_k W2t[m][k] * W1[n][k] = W12^T[m][n], split out ---
    dim3 gw(DD / 128, (DD + 63) / 64);       // (2, 4) = 8 blocks
    gemm_k<true, false><<<gw, 512, 0, stream>>>(WTH(1), WTL(1), WTH(0), WTL(0),
                                                nullptr, WTH(9), WTL(9),
                                                nullptr, nullptr, nullptr, nullptr, DD);

    // --- x split ---
    cvt_split_k<<<(int)((ND + 255) / 256), 256, 0, stream>>>(x, P0h, P0l, (int)ND);

    dim3 gg(DD / 128, (NNODES + 63) / 64);   // (2, 313) = 626 blocks
    const int nodeBlocks = (NNODES + 3) / 4;

    // h0 = x @ W12 (replaces the two chained x@W1, t@W2 gemms)
    gemm_k<true, false><<<gg, 512, 0, stream>>>(P0h, P0l, WTH(9), WTL(9), nullptr, P1h, P1l,
                                                nullptr, nullptr, nullptr, nullptr, NNODES);

    // 6 GAT layers: h (P1 split) -> hw (bufA fp32) + fused dots -> agg -> h (P1 split)
    for (int l = 0; l < 6; ++l) {
        gemm_k<false, true><<<gg, 512, 0, stream>>>(P1h, P1l, WTH(2 + l), WTL(2 + l),
                                                    bufA, nullptr, nullptr,
                                                    a_src + (size_t)l * DD, a_dst + (size_t)l * DD,
                                                    es01, ed01, NNODES);
        if (l < 5)
            gat_agg_k<false><<<nodeBlocks, 256, 0, stream>>>(bufA, es01, es01 + ESTR,
                                                             ed01, ed01 + ESTR,
                                                             rowptr, colsrc, ealpha,
                                                             bias + (size_t)l * DD, P1h, P1l);
        else
            gat_agg_k<true><<<nodeBlocks, 256, 0, stream>>>(bufA, es01, es01 + ESTR,
                                                            ed01, ed01 + ESTR,
                                                            rowptr, colsrc, ealpha,
                                                            bias + (size_t)l * DD, P1h, P1l);
    }

    // out = relu(h) @ (W3_top + W3_bot)  (relu already applied in layer-5 agg)
    gemm_k<false, false><<<gg, 512, 0, stream>>>(P1h, P1l, WTH(8), WTL(8), out,
                                                 nullptr, nullptr,
                                                 nullptr, nullptr, nullptr, nullptr, NNODES);
#undef WTH
#undef WTL
}